// Round 1
// 1461.106 us; speedup vs baseline: 1.0151x; 1.0151x over previous
//
#include <hip/hip_runtime.h>
#include <cstddef>

#define HH 76
#define WW 120
#define NPIX (HH*WW)          // 9120
#define AA 9
#define NANCH (NPIX*AA)       // 82080
#define TOPN 300
#define CIN 1024
#define CMID 512
#define FCDIM 2048
#define KFC (CIN*49)          // 50176
#define PW 128
#define PROWS (78*128)        // 9984 padded pixel rows
#define FPIX_ROWS (PROWS + 8)

typedef __attribute__((ext_vector_type(8))) short short8;
typedef __attribute__((ext_vector_type(4))) float f32x4;

__device__ __forceinline__ float bf2f(unsigned short h) {
    return __uint_as_float(((unsigned int)h) << 16);
}
__device__ __forceinline__ unsigned short f2bf(float f) {
    unsigned int u = __float_as_uint(f);
    unsigned int r = (u + 0x7FFFu + ((u >> 16) & 1u)) >> 16;
    return (unsigned short)r;
}

// async global->LDS, 16B per lane. LDS dest = wave-uniform base + lane*16.
__device__ __forceinline__ void gld16(const unsigned short* g, unsigned short* l) {
    __builtin_amdgcn_global_load_lds(
        (const __attribute__((address_space(1))) unsigned int*)(g),
        (__attribute__((address_space(3))) unsigned int*)(l),
        16, 0, 0);
}

// ---------------- zero init ----------------
__global__ void zero_kernel(float* __restrict__ p, int n) {
    int i = blockIdx.x * 256 + threadIdx.x;
    if (i < n) p[i] = 0.f;
}
__global__ void zero4_kernel(float4* __restrict__ p, int n4) {
    int i = blockIdx.x * 256 + threadIdx.x;
    if (i < n4) p[i] = make_float4(0.f, 0.f, 0.f, 0.f);
}

// ---------------- Fpix fill: [ic][px] fp32 -> [padded px][ic] bf16 ----------------
__global__ __launch_bounds__(256) void fpix_fill_kernel(const float* __restrict__ F,
                                                        unsigned short* __restrict__ Fpix) {
    __shared__ float s[64][65];
    int px0 = blockIdx.x * 64, ic0 = blockIdx.y * 64;
    int t = threadIdx.x;
#pragma unroll 4
    for (int i = 0; i < 16; i++) {
        int ic = (t >> 6) + i * 4;
        int px = px0 + (t & 63);
        float v = (px < NPIX) ? F[(size_t)(ic0 + ic) * NPIX + px] : 0.f;
        s[t & 63][ic] = v;
    }
    __syncthreads();
    int pxl = t >> 2;
    int px = px0 + pxl;
    if (px < NPIX) {
        int h = px / 120, w = px - h * 120;
        size_t prow = (size_t)(h + 1) * PW + (w + 1);
        unsigned short* dst = Fpix + prow * 1024 + ic0 + (t & 3) * 16;
#pragma unroll
        for (int u = 0; u < 16; u++) dst[u] = f2bf(s[pxl][(t & 3) * 16 + u]);
    }
}

// ---------------- Wb fill: [ocic][9] fp32 -> [tap][ocic] bf16 (LDS transpose) ----------------
__global__ __launch_bounds__(256) void wb_fill_kernel(const float* __restrict__ Wsrc,
                                                      unsigned short* __restrict__ Wb) {
    __shared__ float s[2304];
    int r0 = blockIdx.x * 256;
    int t = threadIdx.x;
    const float4* src4 = (const float4*)(Wsrc + (size_t)r0 * 9);
#pragma unroll
    for (int i = 0; i < 3; i++) {
        int idx = t + 256 * i;
        if (idx < 576) *(float4*)&s[idx * 4] = src4[idx];
    }
    __syncthreads();
#pragma unroll
    for (int tap = 0; tap < 9; tap++)
        Wb[(size_t)tap * 524288 + r0 + t] = f2bf(s[t * 9 + tap]);
}

// ---------------- conv 3x3 via MFMA implicit GEMM -> rpn pixel-major [px][512] ----------------
// T3 minimum-2-phase structure: global_load_lds staging, double-buffered LDS,
// BK=64, ONE barrier per K-chunk (144 chunks). Grid (8 octs, 76 rows) x 256 thr.
__global__ __launch_bounds__(256) void conv_mfma_kernel(
    const unsigned short* __restrict__ Fpix,
    const unsigned short* __restrict__ Wb,
    const float* __restrict__ Bs,
    unsigned short* __restrict__ out) {       // [9120][512] bf16
    __shared__ __align__(16) unsigned short As[2][8 * 128 * 8];  // [buf][q 0..7][px 0..127][8 ic]
    __shared__ __align__(16) unsigned short Ws[2][8 * 64 * 8];   // [buf][q 0..7][oc 0..63][8 ic]
    const int tid = threadIdx.x;
    const int oct = blockIdx.x;
    const int h = blockIdx.y;
    const int lane = tid & 63, wv = tid >> 6;
    const int lane16 = lane & 15, quad = lane >> 4;
    const int wave_px = (wv & 1) * 64, wave_oc = (wv >> 1) * 32;

    const int apx = tid & 127;    // A: pixel within row tile
    const int aqh = tid >> 7;     // A: 0..1
    const int boc = tid & 63;     // B: oc within tile
    const int bqh = tid >> 6;     // B: 0..3
    const int wvb = wv * 64;      // wave slot base

    f32x4 acc[4][2];
#pragma unroll
    for (int mi = 0; mi < 4; mi++)
#pragma unroll
        for (int ni = 0; ni < 2; ni++) acc[mi][ni] = (f32x4){0.f, 0.f, 0.f, 0.f};

    // chunk cc in [0,144): tap = cc>>4, ic0 = (cc&15)*64.
    // A slots: slot = u*256 + tid -> q = 2u+aqh, px = apx  (dest linear in tid per wave)
    // B slots: slot = u*256 + tid -> q = 4u+bqh, oc = boc
#define CONV_STAGE(cc, Ab, Wsb)                                                           \
    do {                                                                                  \
        int tap_ = (cc) >> 4;                                                             \
        int ic0_ = ((cc) & 15) << 6;                                                      \
        int dh_ = (tap_ * 11) >> 5;                                                       \
        int dw_ = tap_ - dh_ * 3;                                                         \
        const unsigned short* a0_ =                                                       \
            Fpix + (size_t)((h + dh_) * PW + apx + dw_) * 1024 + ic0_ + aqh * 8;          \
        _Pragma("unroll")                                                                 \
        for (int u_ = 0; u_ < 4; u_++)                                                    \
            gld16(a0_ + u_ * 16, (Ab) + (size_t)(u_ * 256 + wvb) * 8);                    \
        const unsigned short* w0_ =                                                       \
            Wb + (size_t)(tap_ * 512 + oct * 64 + boc) * 1024 + ic0_ + bqh * 8;           \
        _Pragma("unroll")                                                                 \
        for (int u_ = 0; u_ < 2; u_++)                                                    \
            gld16(w0_ + u_ * 32, (Wsb) + (size_t)(u_ * 256 + wvb) * 8);                   \
    } while (0)

    CONV_STAGE(0, &As[0][0], &Ws[0][0]);
    __syncthreads();   // drains vmcnt(0): buf0 staged

    int cur = 0;
    for (int c = 0; c < 144; ++c) {
        if (c + 1 < 144) CONV_STAGE(c + 1, &As[cur ^ 1][0], &Ws[cur ^ 1][0]);
        const unsigned short* Ac = &As[cur][0];
        const unsigned short* Wc = &Ws[cur][0];
#pragma unroll
        for (int kk = 0; kk < 2; kk++) {
            short8 af[4], bfr[2];
#pragma unroll
            for (int mi = 0; mi < 4; mi++)
                af[mi] = *(const short8*)&Ac[(size_t)((kk * 4 + quad) * 128 + wave_px +
                                                      mi * 16 + lane16) * 8];
#pragma unroll
            for (int ni = 0; ni < 2; ni++)
                bfr[ni] = *(const short8*)&Wc[(size_t)((kk * 4 + quad) * 64 + wave_oc +
                                                       ni * 16 + lane16) * 8];
#pragma unroll
            for (int mi = 0; mi < 4; mi++)
#pragma unroll
                for (int ni = 0; ni < 2; ni++)
                    acc[mi][ni] = __builtin_amdgcn_mfma_f32_16x16x32_bf16(
                        af[mi], bfr[ni], acc[mi][ni], 0, 0, 0);
        }
        __syncthreads();   // drains next-buf staging + this-buf reads
        cur ^= 1;
    }
#undef CONV_STAGE

    // epilogue -> pixel-major rpn
#pragma unroll
    for (int ni = 0; ni < 2; ni++) {
        int oc = oct * 64 + wave_oc + ni * 16 + lane16;
        float bias = Bs[oc];
#pragma unroll
        for (int mi = 0; mi < 4; mi++) {
#pragma unroll
            for (int r = 0; r < 4; r++) {
                int px = wave_px + mi * 16 + quad * 4 + r;
                if (px < 120)
                    out[(size_t)(h * 120 + px) * 512 + oc] =
                        f2bf(fmaxf(acc[mi][ni][r] + bias, 0.f));
            }
        }
    }
}

// ---------------- heads via MFMA: [9120 px][512] @ [54][512]^T -> cls_s, bbox_p ----------------
// grid 72, block 256. Block tile 128 px x 64 oc (54 used), K=512 in 16 chunks.
__global__ __launch_bounds__(256) void heads_mfma_kernel(
    const unsigned short* __restrict__ rpn,   // [9120][512] bf16
    const float* __restrict__ cw, const float* __restrict__ cb,
    const float* __restrict__ bw, const float* __restrict__ bb,
    float* __restrict__ cls_s, float* __restrict__ bbox_p) {
    __shared__ __align__(16) unsigned short As[128 * 42];
    __shared__ __align__(16) unsigned short Ws[64 * 42];
    const int tid = threadIdx.x;
    const int px0 = blockIdx.x * 128;
    const int lane = tid & 63, wv = tid >> 6;
    const int lane16 = lane & 15, quad = lane >> 4;
    const int wave_px = (wv & 1) * 64, wave_oc = (wv >> 1) * 32;

    f32x4 acc[4][2];
#pragma unroll
    for (int mi = 0; mi < 4; mi++)
#pragma unroll
        for (int ni = 0; ni < 2; ni++) acc[mi][ni] = (f32x4){0.f, 0.f, 0.f, 0.f};

    const int wn = tid >> 2, wseg = tid & 3;   // W staging: n, 8-float segment
    const float* wsrc = (wn < 18) ? (cw + (size_t)wn * 512)
                      : (wn < 54) ? (bw + (size_t)(wn - 18) * 512) : nullptr;

    short8 rA[2];
    float4 rw0, rw1;
    {
        int k0 = 0;
#pragma unroll
        for (int u = 0; u < 2; u++) {
            int lid = tid + 256 * u;
            int row = lid >> 2, seg = lid & 3;
            int px = px0 + row;
            rA[u] = (px < NPIX) ? *(const short8*)(rpn + (size_t)px * 512 + k0 + seg * 8)
                                : (short8){0, 0, 0, 0, 0, 0, 0, 0};
        }
        if (wsrc) {
            rw0 = *(const float4*)(wsrc + k0 + wseg * 8);
            rw1 = *(const float4*)(wsrc + k0 + wseg * 8 + 4);
        } else { rw0 = make_float4(0, 0, 0, 0); rw1 = rw0; }
    }
    for (int c = 0; c < 16; ++c) {
        __syncthreads();
#pragma unroll
        for (int u = 0; u < 2; u++) {
            int lid = tid + 256 * u;
            int row = lid >> 2, seg = lid & 3;
            *(short8*)&As[row * 42 + seg * 8] = rA[u];
        }
        {
            short8 wb;
            float* p0 = (float*)&rw0;
            float* p1 = (float*)&rw1;
#pragma unroll
            for (int v = 0; v < 4; v++) { wb[v] = (short)f2bf(p0[v]); wb[4 + v] = (short)f2bf(p1[v]); }
            *(short8*)&Ws[wn * 42 + wseg * 8] = wb;
        }
        if (c + 1 < 16) {
            int k0 = (c + 1) * 32;
#pragma unroll
            for (int u = 0; u < 2; u++) {
                int lid = tid + 256 * u;
                int row = lid >> 2, seg = lid & 3;
                int px = px0 + row;
                rA[u] = (px < NPIX) ? *(const short8*)(rpn + (size_t)px * 512 + k0 + seg * 8)
                                    : (short8){0, 0, 0, 0, 0, 0, 0, 0};
            }
            if (wsrc) {
                rw0 = *(const float4*)(wsrc + k0 + wseg * 8);
                rw1 = *(const float4*)(wsrc + k0 + wseg * 8 + 4);
            }
        }
        __syncthreads();
        short8 af[4], bfr[2];
#pragma unroll
        for (int mi = 0; mi < 4; mi++)
            af[mi] = *(const short8*)&As[(wave_px + mi * 16 + lane16) * 42 + quad * 8];
#pragma unroll
        for (int ni = 0; ni < 2; ni++)
            bfr[ni] = *(const short8*)&Ws[(wave_oc + ni * 16 + lane16) * 42 + quad * 8];
#pragma unroll
        for (int mi = 0; mi < 4; mi++)
#pragma unroll
            for (int ni = 0; ni < 2; ni++)
                acc[mi][ni] = __builtin_amdgcn_mfma_f32_16x16x32_bf16(af[mi], bfr[ni],
                                                                     acc[mi][ni], 0, 0, 0);
    }
#pragma unroll
    for (int ni = 0; ni < 2; ni++) {
        int oc = wave_oc + ni * 16 + lane16;
        float* dst;
        float bias;
        if (oc < 18) { dst = cls_s + (size_t)oc * NPIX; bias = cb[oc]; }
        else if (oc < 54) { dst = bbox_p + (size_t)(oc - 18) * NPIX; bias = bb[oc - 18]; }
        else continue;
#pragma unroll
        for (int mi = 0; mi < 4; mi++) {
            int pxb = px0 + wave_px + mi * 16 + quad * 4;
            if (pxb < NPIX) {
                float4 v = make_float4(acc[mi][ni][0] + bias, acc[mi][ni][1] + bias,
                                       acc[mi][ni][2] + bias, acc[mi][ni][3] + bias);
                *(float4*)(dst + pxb) = v;
            }
        }
    }
}

// ---------------- decode ----------------
__global__ void decode_kernel(const float* __restrict__ cls_s, const float* __restrict__ bbox_p,
                              const float* __restrict__ anchors,
                              unsigned int* __restrict__ keys, float* __restrict__ boxes) {
    int i = blockIdx.x * 256 + threadIdx.x;
    if (i >= NANCH) return;
    int pix = i / AA;
    int a = i - pix * AA;
    float s0 = cls_s[(size_t)a * NPIX + pix];
    float s1 = cls_s[(size_t)(AA + a) * NPIX + pix];
    float d = s1 - s0;
    unsigned int u = __float_as_uint(d);
    keys[i] = (u & 0x80000000u) ? ~u : (u | 0x80000000u);

    float dx = bbox_p[(size_t)(4 * a + 0) * NPIX + pix];
    float dy = bbox_p[(size_t)(4 * a + 1) * NPIX + pix];
    float dw = bbox_p[(size_t)(4 * a + 2) * NPIX + pix];
    float dh = bbox_p[(size_t)(4 * a + 3) * NPIX + pix];
    float ax1 = anchors[(size_t)i * 4 + 0];
    float ay1 = anchors[(size_t)i * 4 + 1];
    float ax2 = anchors[(size_t)i * 4 + 2];
    float ay2 = anchors[(size_t)i * 4 + 3];
    float aw = ax2 - ax1 + 1.f;
    float ah = ay2 - ay1 + 1.f;
    float acx = ax1 + 0.5f * aw;
    float acy = ay1 + 0.5f * ah;
    float pcx = dx * aw + acx;
    float pcy = dy * ah + acy;
    float pw = __expf(dw) * aw;
    float ph = __expf(dh) * ah;
    const float XMAX = 16.f * WW - 1.f;
    const float YMAX = 16.f * HH - 1.f;
    boxes[(size_t)i * 4 + 0] = fminf(fmaxf(pcx - 0.5f * pw, 0.f), XMAX);
    boxes[(size_t)i * 4 + 1] = fminf(fmaxf(pcy - 0.5f * ph, 0.f), YMAX);
    boxes[(size_t)i * 4 + 2] = fminf(fmaxf(pcx + 0.5f * pw, 0.f), XMAX);
    boxes[(size_t)i * 4 + 3] = fminf(fmaxf(pcy + 0.5f * ph, 0.f), YMAX);
}

// ---------------- exact top-k ----------------
__global__ __launch_bounds__(1024) void topk_kernel(const unsigned int* __restrict__ keys,
                                                    int* __restrict__ top_idx) {
    const int N = NANCH, K = TOPN;
    __shared__ unsigned int s_prefix;
    __shared__ int s_k;
    __shared__ unsigned int hist[256];
    __shared__ int s_ngt, s_neq;
    __shared__ unsigned long long s_sel[512];
    __shared__ int s_eq[1024];
    int tid = threadIdx.x;
    if (tid == 0) { s_prefix = 0u; s_k = K; }
    __syncthreads();

    for (int d = 3; d >= 0; --d) {
        if (tid < 256) hist[tid] = 0u;
        __syncthreads();
        unsigned int pfx = s_prefix;
        unsigned int maskHigh = (d == 3) ? 0u : ~((1u << ((d + 1) * 8)) - 1u);
        int shift = d * 8;
        for (int i = tid; i < N; i += 1024) {
            unsigned int k = keys[i];
            if ((k & maskHigh) == (pfx & maskHigh))
                atomicAdd(&hist[(k >> shift) & 255u], 1u);
        }
        __syncthreads();
        if (tid == 0) {
            int kk = s_k;
            int cum = 0;
            unsigned int sel = 0;
            for (int v = 255; v >= 0; v--) {
                int hcnt = (int)hist[v];
                if (cum + hcnt >= kk) { sel = (unsigned int)v; s_k = kk - cum; break; }
                cum += hcnt;
            }
            s_prefix = pfx | (sel << shift);
        }
        __syncthreads();
    }
    unsigned int T = s_prefix;
    int krem = s_k;
    if (tid == 0) { s_ngt = 0; s_neq = 0; }
    __syncthreads();
    for (int i = tid; i < N; i += 1024) {
        unsigned int k = keys[i];
        if (k > T) {
            int p = atomicAdd(&s_ngt, 1);
            if (p < 512)
                s_sel[p] = ((unsigned long long)k << 32) | (unsigned int)(~(unsigned int)i);
        } else if (k == T) {
            int p = atomicAdd(&s_neq, 1);
            if (p < 1024) s_eq[p] = i;
        }
    }
    __syncthreads();
    int ngt = min(s_ngt, 512);
    int neq = min(s_neq, 1024);
    for (int e = tid; e < neq; e += 1024) {
        int idx = s_eq[e];
        int rank = 0;
        for (int j = 0; j < neq; j++)
            if (s_eq[j] < idx) rank++;
        if (rank < krem && ngt + rank < 512)
            s_sel[ngt + rank] = ((unsigned long long)T << 32) | (unsigned int)(~(unsigned int)idx);
    }
    __syncthreads();
    for (int p = K + tid; p < 512; p += 1024) s_sel[p] = 0ULL;
    __syncthreads();
    for (unsigned int k2 = 2; k2 <= 512; k2 <<= 1) {
        for (unsigned int j = k2 >> 1; j > 0; j >>= 1) {
            if (tid < 512) {
                int i = tid;
                int ixj = i ^ (int)j;
                if (ixj > i) {
                    unsigned long long a = s_sel[i], cc = s_sel[ixj];
                    bool up = ((i & k2) == 0);
                    if (up ? (a > cc) : (a < cc)) { s_sel[i] = cc; s_sel[ixj] = a; }
                }
            }
            __syncthreads();
        }
    }
    if (tid < K)
        top_idx[tid] = (int)(~(unsigned int)(s_sel[511 - tid] & 0xFFFFFFFFull));
}

// ---------------- roi align from Fpix -> pooled (n,q,c) bf16 ----------------
__global__ __launch_bounds__(256) void roialign_kernel(
    const unsigned short* __restrict__ Fpix, const float* __restrict__ boxes,
    const int* __restrict__ top_idx, unsigned short* __restrict__ pooled) {
    int n = blockIdx.x;
    int q = blockIdx.y;
    int ph = q / 7, pw = q - ph * 7;
    int bi = top_idx[n];
    float x1 = boxes[(size_t)bi * 4 + 0] * (1.f / 16.f);
    float y1 = boxes[(size_t)bi * 4 + 1] * (1.f / 16.f);
    float x2 = boxes[(size_t)bi * 4 + 2] * (1.f / 16.f);
    float y2 = boxes[(size_t)bi * 4 + 3] * (1.f / 16.f);
    float gx = (pw + 0.5f) / 7.f;
    float gy = (ph + 0.5f) / 7.f;
    float xs = fminf(fmaxf(x1 + (x2 - x1) * gx, 0.f), (float)(WW - 1));
    float ys = fminf(fmaxf(y1 + (y2 - y1) * gy, 0.f), (float)(HH - 1));
    float x0f = floorf(xs), y0f = floorf(ys);
    int x0 = (int)x0f, y0 = (int)y0f;
    int x1i = min(x0 + 1, WW - 1);
    int y1i = min(y0 + 1, HH - 1);
    float wx = xs - x0f, wy = ys - y0f;
    float w00 = (1.f - wy) * (1.f - wx), w01 = (1.f - wy) * wx;
    float w10 = wy * (1.f - wx), w11 = wy * wx;
    const unsigned short* r00 = Fpix + (size_t)((y0 + 1) * PW + x0 + 1) * 1024;
    const unsigned short* r01 = Fpix + (size_t)((y0 + 1) * PW + x1i + 1) * 1024;
    const unsigned short* r10 = Fpix + (size_t)((y1i + 1) * PW + x0 + 1) * 1024;
    const unsigned short* r11 = Fpix + (size_t)((y1i + 1) * PW + x1i + 1) * 1024;
    unsigned short* dst = pooled + (size_t)n * KFC + (size_t)q * CIN;
    int c = threadIdx.x * 4;
    ushort4 a = *(const ushort4*)(r00 + c);
    ushort4 b = *(const ushort4*)(r01 + c);
    ushort4 cc = *(const ushort4*)(r10 + c);
    ushort4 d = *(const ushort4*)(r11 + c);
    ushort4 o;
    o.x = f2bf(w00 * bf2f(a.x) + w01 * bf2f(b.x) + w10 * bf2f(cc.x) + w11 * bf2f(d.x));
    o.y = f2bf(w00 * bf2f(a.y) + w01 * bf2f(b.y) + w10 * bf2f(cc.y) + w11 * bf2f(d.y));
    o.z = f2bf(w00 * bf2f(a.z) + w01 * bf2f(b.z) + w10 * bf2f(cc.z) + w11 * bf2f(d.z));
    o.w = f2bf(w00 * bf2f(a.w) + w01 * bf2f(b.w) + w10 * bf2f(cc.w) + w11 * bf2f(d.w));
    *(ushort4*)(dst + c) = o;
}

// ---------------- FC GEMM via MFMA: fc7 += pooled(300x50176 bf16) @ fc_w(fp32->bf16) ----------
// grid 256: kz = b&7 (XCD-affine), j-tile = b>>3 (64 cols). Block: 320 px x 64 col.
__global__ __launch_bounds__(256) void fc_mfma_kernel(
    const unsigned short* __restrict__ pooled, const float* __restrict__ fc_w,
    float* __restrict__ fc7) {
    __shared__ __align__(16) unsigned short As[320 * 42];
    __shared__ __align__(16) unsigned short Ws[64 * 42];
    const int tid = threadIdx.x;
    const int b = blockIdx.x;
    const int kz = b & 7;
    const int j0 = (b >> 3) * 64;
    const int lane = tid & 63, wv = tid >> 6;
    const int lane16 = lane & 15, quad = lane >> 4;
    const int m0 = wv * 80;
    const int kbase = kz * 6272;
    const int g = tid >> 4;              // W staging: krow pair 2g, 2g+1
    const int col4 = (tid & 15) * 4;

    f32x4 acc[5][4];
#pragma unroll
    for (int mi = 0; mi < 5; mi++)
#pragma unroll
        for (int ni = 0; ni < 4; ni++) acc[mi][ni] = (f32x4){0.f, 0.f, 0.f, 0.f};

    short8 rA[5];
    float4 rW0[2], rW1[2];

#define LOAD_A(cIdx)                                                              \
    {                                                                             \
        int k0_ = kbase + (cIdx) * 32;                                            \
        _Pragma("unroll")                                                         \
        for (int i = 0; i < 5; i++) {                                             \
            int lid = tid + 256 * i;                                              \
            int row = lid >> 2, seg = lid & 3;                                    \
            rA[i] = (row < TOPN)                                                  \
                  ? *(const short8*)(pooled + (size_t)row * KFC + k0_ + seg * 8)  \
                  : (short8){0, 0, 0, 0, 0, 0, 0, 0};                             \
        }                                                                         \
    }
#define LOAD_W(cIdx, dst)                                                         \
    {                                                                             \
        int k0_ = kbase + (cIdx) * 32;                                            \
        int q_ = k0_ >> 10, c0_ = k0_ & 1023;                                     \
        _Pragma("unroll")                                                         \
        for (int u = 0; u < 2; u++)                                               \
            dst[u] = *(const float4*)(fc_w +                                      \
                ((size_t)(c0_ + 2 * g + u) * 49 + q_) * FCDIM + j0 + col4);       \
    }

    LOAD_A(0);
    LOAD_W(0, rW0);
    LOAD_W(1, rW1);

    for (int c = 0; c < 196; ++c) {
        __syncthreads();
#pragma unroll
        for (int i = 0; i < 5; i++) {
            int lid = tid + 256 * i;
            int row = lid >> 2, seg = lid & 3;
            *(short8*)&As[row * 42 + seg * 8] = rA[i];
        }
        {
            float* p0 = (float*)&rW0[0];
            float* p1 = (float*)&rW0[1];
#pragma unroll
            for (int v = 0; v < 4; v++) {
                unsigned int pk = (unsigned int)f2bf(p0[v]) | ((unsigned int)f2bf(p1[v]) << 16);
                *(unsigned int*)&Ws[(col4 + v) * 42 + 2 * g] = pk;
            }
        }
        if (c + 1 < 196) LOAD_A(c + 1);
        rW0[0] = rW1[0]; rW0[1] = rW1[1];
        if (c + 2 < 196) LOAD_W(c + 2, rW1);
        __syncthreads();
        short8 af[5], bfr[4];
#pragma unroll
        for (int mi = 0; mi < 5; mi++)
            af[mi] = *(const short8*)&As[(m0 + mi * 16 + lane16) * 42 + quad * 8];
#pragma unroll
        for (int ni = 0; ni < 4; ni++)
            bfr[ni] = *(const short8*)&Ws[(ni * 16 + lane16) * 42 + quad * 8];
#pragma unroll
        for (int mi = 0; mi < 5; mi++)
#pragma unroll
            for (int ni = 0; ni < 4; ni++)
                acc[mi][ni] = __builtin_amdgcn_mfma_f32_16x16x32_bf16(af[mi], bfr[ni],
                                                                     acc[mi][ni], 0, 0, 0);
    }
#undef LOAD_A
#undef LOAD_W
#pragma unroll
    for (int mi = 0; mi < 5; mi++) {
#pragma unroll
        for (int r = 0; r < 4; r++) {
            int m = m0 + mi * 16 + quad * 4 + r;
            if (m < TOPN) {
#pragma unroll
                for (int ni = 0; ni < 4; ni++)
                    atomicAdd(&fc7[(size_t)m * FCDIM + j0 + ni * 16 + lane16], acc[mi][ni][r]);
            }
        }
    }
}

// ---------------- fc7 bias + relu ----------------
__global__ void bias_relu_kernel(float* __restrict__ fc7, const float* __restrict__ fc_b) {
    int i = blockIdx.x * 256 + threadIdx.x;
    if (i < TOPN * FCDIM)
        fc7[i] = fmaxf(fc7[i] + fc_b[i & (FCDIM - 1)], 0.f);
}

// ---------------- head GEMMs ----------------
__global__ __launch_bounds__(128) void head_gemm_kernel(
    const float* __restrict__ fc7,
    const float* __restrict__ cw, const float* __restrict__ cb,
    const float* __restrict__ bw, const float* __restrict__ bb,
    float* __restrict__ cls_score, float* __restrict__ bbox_pred) {
    int n = blockIdx.x;
    __shared__ float row[FCDIM];
    for (int k = threadIdx.x; k < FCDIM; k += 128) row[k] = fc7[(size_t)n * FCDIM + k];
    __syncthreads();
    int t = threadIdx.x;
    if (t < 21) {
        float acc = 0.f;
        for (int k = 0; k < FCDIM; k += 4) {
#pragma unroll
            for (int u = 0; u < 4; u++) acc += row[k + u] * cw[(size_t)(k + u) * 21 + t];
        }
        cls_score[n * 21 + t] = acc + cb[t];
    } else if (t < 105) {
        int oc = t - 21;
        float acc = 0.f;
        for (int k = 0; k < FCDIM; k += 4) {
#pragma unroll
            for (int u = 0; u < 4; u++) acc += row[k + u] * bw[(size_t)(k + u) * 84 + oc];
        }
        bbox_pred[n * 84 + oc] = acc + bb[oc];
    }
}

// ---------------- losses ----------------
__device__ __forceinline__ void block_atomic_acc(float v, float* dst) {
    for (int o = 32; o > 0; o >>= 1) v += __shfl_down(v, o);
    if ((threadIdx.x & 63) == 0) atomicAdd(dst, v);
}

__global__ void loss_rpn_ce_kernel(const float* __restrict__ cls_s,
                                   const int* __restrict__ labels, float* __restrict__ acc) {
    int i = blockIdx.x * 256 + threadIdx.x;
    float ce = 0.f, cnt = 0.f;
    if (i < NANCH) {
        int lab = labels[i];
        if (lab != -1) {
            int a = i / NPIX, pix = i - a * NPIX;
            float s0 = cls_s[(size_t)a * NPIX + pix];
            float s1 = cls_s[(size_t)(AA + a) * NPIX + pix];
            float m = fmaxf(s0, s1);
            float lse = m + logf(expf(s0 - m) + expf(s1 - m));
            ce = lse - (lab ? s1 : s0);
            cnt = 1.f;
        }
    }
    block_atomic_acc(ce, &acc[0]);
    block_atomic_acc(cnt, &acc[1]);
}

__global__ void loss_rpn_bbox_kernel(const float* __restrict__ bbox_p,
                                     const float* __restrict__ tgt,
                                     const float* __restrict__ biw,
                                     const float* __restrict__ bow, float* __restrict__ acc) {
    int e = blockIdx.x * 256 + threadIdx.x;
    float contrib = 0.f;
    if (e < NPIX * 36) {
        int pix = e / 36, c = e - pix * 36;
        float pred = bbox_p[(size_t)c * NPIX + pix];
        float d = biw[e] * (pred - tgt[e]);
        float ad = fabsf(d);
        float l = (ad < (1.f / 9.f)) ? d * d * 4.5f : ad - (1.f / 18.f);
        contrib = bow[e] * l;
    }
    block_atomic_acc(contrib, &acc[2]);
}

__global__ void loss_cls_kernel(const float* __restrict__ cls_score,
                                const int* __restrict__ labels, float* __restrict__ acc) {
    int n = blockIdx.x * 256 + threadIdx.x;
    float ce = 0.f;
    if (n < TOPN) {
        const float* lg = cls_score + n * 21;
        float m = lg[0];
        for (int j = 1; j < 21; j++) m = fmaxf(m, lg[j]);
        float s = 0.f;
        for (int j = 0; j < 21; j++) s += expf(lg[j] - m);
        ce = m + logf(s) - lg[labels[n]];
    }
    block_atomic_acc(ce, &acc[3]);
}

__global__ void loss_roi_bbox_kernel(const float* __restrict__ bbox_pred,
                                     const float* __restrict__ tgt,
                                     const float* __restrict__ biw,
                                     const float* __restrict__ bow, float* __restrict__ acc) {
    int e = blockIdx.x * 256 + threadIdx.x;
    float contrib = 0.f;
    if (e < TOPN * 84) {
        float d = biw[e] * (bbox_pred[e] - tgt[e]);
        float ad = fabsf(d);
        float l = (ad < 1.f) ? 0.5f * d * d : ad - 0.5f;
        contrib = bow[e] * l;
    }
    block_atomic_acc(contrib, &acc[4]);
}

__global__ void finalize_kernel(const float* __restrict__ acc, float* __restrict__ out) {
    out[0] = acc[0] / fmaxf(acc[1], 1.f) + acc[2]
           + acc[3] * (1.f / TOPN) + acc[4] * (1.f / TOPN);
}

// ---------------- launch ----------------
extern "C" void kernel_launch(void* const* d_in, const int* in_sizes, int n_in,
                              void* d_out, int out_size, void* d_ws, size_t ws_size,
                              hipStream_t stream) {
    const float* net_conv   = (const float*)d_in[0];
    const float* rpn_w      = (const float*)d_in[1];
    const float* rpn_b      = (const float*)d_in[2];
    const float* rpn_cls_w  = (const float*)d_in[3];
    const float* rpn_cls_b  = (const float*)d_in[4];
    const float* rpn_bbox_w = (const float*)d_in[5];
    const float* rpn_bbox_b = (const float*)d_in[6];
    const float* fc_w       = (const float*)d_in[7];
    const float* fc_b       = (const float*)d_in[8];
    const float* cls_w      = (const float*)d_in[9];
    const float* cls_b      = (const float*)d_in[10];
    const float* bbox_w     = (const float*)d_in[11];
    const float* bbox_b     = (const float*)d_in[12];
    const float* anchors    = (const float*)d_in[13];
    const float* rpn_bt     = (const float*)d_in[14];
    const float* rpn_biw    = (const float*)d_in[15];
    const float* rpn_bow    = (const float*)d_in[16];
    const float* roi_bt     = (const float*)d_in[17];
    const float* roi_biw    = (const float*)d_in[18];
    const float* roi_bow    = (const float*)d_in[19];
    const int* rpn_labels   = (const int*)d_in[20];
    const int* roi_labels   = (const int*)d_in[21];

    char* base = (char*)d_ws;
    unsigned short* Fpix = (unsigned short*)base;
    const size_t FPIX_BYTES = (size_t)FPIX_ROWS * 1024 * 2;  // 20,463,616
    unsigned short* Wb = (unsigned short*)(base + FPIX_BYTES);
    unsigned short* rpn = (unsigned short*)(base + 29900800);  // [9120][512] bf16
    unsigned short* pooled = (unsigned short*)(base + FPIX_BYTES);
    size_t off = 50569216;
    float* cls_s = (float*)(base + off);      off += 656640;
    float* bbox_p = (float*)(base + off);     off += 1313280;
    unsigned int* keys = (unsigned int*)(base + off); off += 328448;
    float* boxes = (float*)(base + off);      off += 1313280;
    int* top_idx = (int*)(base + off);        off += 1280;
    float* cls_score = (float*)(base + off);  off += 25600;
    float* bbox_pred = (float*)(base + off);  off += 100864;
    float* fc7 = (float*)(base + off);        off += 2457600;
    float* accum = (float*)(base + off);      off += 256;
    float* out = (float*)d_out;

    zero4_kernel<<<(int)((FPIX_BYTES / 16 + 255) / 256), 256, 0, stream>>>((float4*)Fpix,
                                                                           (int)(FPIX_BYTES / 16));
    fpix_fill_kernel<<<dim3(143, 16), 256, 0, stream>>>(net_conv, Fpix);
    wb_fill_kernel<<<2048, 256, 0, stream>>>(rpn_w, Wb);
    zero_kernel<<<2401, 256, 0, stream>>>(fc7, TOPN * FCDIM + 16);

    conv_mfma_kernel<<<dim3(8, 76), 256, 0, stream>>>(Fpix, Wb, rpn_b, rpn);
    heads_mfma_kernel<<<72, 256, 0, stream>>>(rpn, rpn_cls_w, rpn_cls_b,
                                              rpn_bbox_w, rpn_bbox_b, cls_s, bbox_p);
    decode_kernel<<<(NANCH + 255) / 256, 256, 0, stream>>>(cls_s, bbox_p, anchors, keys, boxes);
    topk_kernel<<<1, 1024, 0, stream>>>(keys, top_idx);
    roialign_kernel<<<dim3(300, 49), 256, 0, stream>>>(Fpix, boxes, top_idx, pooled);
    fc_mfma_kernel<<<256, 256, 0, stream>>>(pooled, fc_w, fc7);
    bias_relu_kernel<<<(TOPN * FCDIM + 255) / 256, 256, 0, stream>>>(fc7, fc_b);
    head_gemm_kernel<<<300, 128, 0, stream>>>(fc7, cls_w, cls_b, bbox_w, bbox_b,
                                              cls_score, bbox_pred);
    loss_rpn_ce_kernel<<<(NANCH + 255) / 256, 256, 0, stream>>>(cls_s, rpn_labels, accum);
    loss_rpn_bbox_kernel<<<(NPIX * 36 + 255) / 256, 256, 0, stream>>>(bbox_p, rpn_bt,
                                                                      rpn_biw, rpn_bow, accum);
    loss_cls_kernel<<<2, 256, 0, stream>>>(cls_score, roi_labels, accum);
    loss_roi_bbox_kernel<<<(TOPN * 84 + 255) / 256, 256, 0, stream>>>(bbox_pred, roi_bt,
                                                                      roi_biw, roi_bow, accum);
    finalize_kernel<<<1, 1, 0, stream>>>(accum, out);
}

// Round 2
// 1272.113 us; speedup vs baseline: 1.1659x; 1.1486x over previous
//
#include <hip/hip_runtime.h>
#include <cstddef>

#define HH 76
#define WW 120
#define NPIX (HH*WW)          // 9120
#define AA 9
#define NANCH (NPIX*AA)       // 82080
#define TOPN 300
#define CIN 1024
#define CMID 512
#define FCDIM 2048
#define KFC (CIN*49)          // 50176
#define PW 128
#define PROWS (78*128)        // 9984 padded pixel rows
#define FPIX_ROWS (PROWS + 8)

typedef __attribute__((ext_vector_type(8))) short short8;
typedef __attribute__((ext_vector_type(4))) float f32x4;

__device__ __forceinline__ float bf2f(unsigned short h) {
    return __uint_as_float(((unsigned int)h) << 16);
}
__device__ __forceinline__ unsigned short f2bf(float f) {
    unsigned int u = __float_as_uint(f);
    unsigned int r = (u + 0x7FFFu + ((u >> 16) & 1u)) >> 16;
    return (unsigned short)r;
}

// async global->LDS, 16B per lane. LDS dest = wave-uniform base + lane*16.
__device__ __forceinline__ void gld16(const unsigned short* g, unsigned short* l) {
    __builtin_amdgcn_global_load_lds(
        (const __attribute__((address_space(1))) unsigned int*)(g),
        (__attribute__((address_space(3))) unsigned int*)(l),
        16, 0, 0);
}

// ---------------- zero init ----------------
__global__ void zero_kernel(float* __restrict__ p, int n) {
    int i = blockIdx.x * 256 + threadIdx.x;
    if (i < n) p[i] = 0.f;
}
__global__ void zero4_kernel(float4* __restrict__ p, int n4) {
    int i = blockIdx.x * 256 + threadIdx.x;
    if (i < n4) p[i] = make_float4(0.f, 0.f, 0.f, 0.f);
}

// ---------------- Fpix fill: [ic][px] fp32 -> [padded px][ic] bf16 ----------------
__global__ __launch_bounds__(256) void fpix_fill_kernel(const float* __restrict__ F,
                                                        unsigned short* __restrict__ Fpix) {
    __shared__ float s[64][65];
    int px0 = blockIdx.x * 64, ic0 = blockIdx.y * 64;
    int t = threadIdx.x;
#pragma unroll 4
    for (int i = 0; i < 16; i++) {
        int ic = (t >> 6) + i * 4;
        int px = px0 + (t & 63);
        float v = (px < NPIX) ? F[(size_t)(ic0 + ic) * NPIX + px] : 0.f;
        s[t & 63][ic] = v;
    }
    __syncthreads();
    int pxl = t >> 2;
    int px = px0 + pxl;
    if (px < NPIX) {
        int h = px / 120, w = px - h * 120;
        size_t prow = (size_t)(h + 1) * PW + (w + 1);
        unsigned short* dst = Fpix + prow * 1024 + ic0 + (t & 3) * 16;
#pragma unroll
        for (int u = 0; u < 16; u++) dst[u] = f2bf(s[pxl][(t & 3) * 16 + u]);
    }
}

// ---------------- Wb fill: [ocic][9] fp32 -> [tap][ocic] bf16 (LDS transpose) ----------------
__global__ __launch_bounds__(256) void wb_fill_kernel(const float* __restrict__ Wsrc,
                                                      unsigned short* __restrict__ Wb) {
    __shared__ float s[2304];
    int r0 = blockIdx.x * 256;
    int t = threadIdx.x;
    const float4* src4 = (const float4*)(Wsrc + (size_t)r0 * 9);
#pragma unroll
    for (int i = 0; i < 3; i++) {
        int idx = t + 256 * i;
        if (idx < 576) *(float4*)&s[idx * 4] = src4[idx];
    }
    __syncthreads();
#pragma unroll
    for (int tap = 0; tap < 9; tap++)
        Wb[(size_t)tap * 524288 + r0 + t] = f2bf(s[t * 9 + tap]);
}

// ---------------- conv 3x3 via MFMA implicit GEMM -> rpn pixel-major [px][512] ----------------
// v3: XOR-swizzled LDS rows (T2, both-sides rule) + XCD-affine h-chunk remap (T1).
// LDS layout: As[px][8 seg16], phys_seg = seg ^ (px&7); Ws[oc][8 seg16], phys_seg = seg ^ (oc&7).
// Staging lanes fetch the inverse-permuted global source so gld_lds linear dest matches.
// Grid 640 = 8 XCD x (8 oct x 10 h): XCD x owns h in [10x, 10x+10) for ALL octs ->
// per-XCD A working set ~3MB (L2-resident), kills the x8 cross-XCD A duplication.
__global__ __launch_bounds__(256) void conv_mfma_kernel(
    const unsigned short* __restrict__ Fpix,
    const unsigned short* __restrict__ Wb,
    const float* __restrict__ Bs,
    unsigned short* __restrict__ out) {       // [9120][512] bf16
    __shared__ __align__(16) unsigned short As[2][128 * 64];  // [buf][px][64 ic-shorts]
    __shared__ __align__(16) unsigned short Ws[2][64 * 64];   // [buf][oc][64 ic-shorts]
    const int tid = threadIdx.x;
    const int flat = blockIdx.x;
    const int xcd = flat & 7;
    const int r = flat >> 3;           // 0..79
    const int oct = r & 7;
    const int h = xcd * 10 + (r >> 3); // h-chunk per XCD
    if (h >= HH) return;
    const int lane = tid & 63, wv = tid >> 6;
    const int lane16 = lane & 15, quad = lane >> 4;
    const int wave_px = (wv & 1) * 64, wave_oc = (wv >> 1) * 32;
    const int wvb = wv * 64;           // wave slot base for staging

    f32x4 acc[4][2];
#pragma unroll
    for (int mi = 0; mi < 4; mi++)
#pragma unroll
        for (int ni = 0; ni < 2; ni++) acc[mi][ni] = (f32x4){0.f, 0.f, 0.f, 0.f};

    // chunk cc in [0,144): tap = cc>>4, ic0 = (cc&15)*64 shorts.
    // A: 4 rounds of 256 lanes; slot = u*256+tid -> px = slot>>3, phys seg sp = slot&7.
    //    global source seg = sp ^ (px&7)  (inverse swizzle).
    // B: 2 rounds; slot -> oc = slot>>3, sp = slot&7; source seg = sp ^ (oc&7).
#define CONV_STAGE(cc, Ab, Wsb)                                                           \
    do {                                                                                  \
        int tap_ = (cc) >> 4;                                                             \
        int ic0_ = ((cc) & 15) << 6;                                                      \
        int dh_ = (tap_ * 11) >> 5;                                                       \
        int dw_ = tap_ - dh_ * 3;                                                         \
        _Pragma("unroll")                                                                 \
        for (int u_ = 0; u_ < 4; u_++) {                                                  \
            int slot_ = u_ * 256 + tid;                                                   \
            int px_ = slot_ >> 3, sp_ = slot_ & 7;                                        \
            const unsigned short* src_ =                                                  \
                Fpix + (size_t)((h + dh_) * PW + px_ + dw_) * 1024 + ic0_                 \
                     + ((sp_ ^ (px_ & 7)) << 3);                                          \
            gld16(src_, (Ab) + (size_t)(u_ * 256 + wvb) * 8);                             \
        }                                                                                 \
        _Pragma("unroll")                                                                 \
        for (int u_ = 0; u_ < 2; u_++) {                                                  \
            int slot_ = u_ * 256 + tid;                                                   \
            int oc_ = slot_ >> 3, sp_ = slot_ & 7;                                        \
            const unsigned short* src_ =                                                  \
                Wb + (size_t)(tap_ * 512 + oct * 64 + oc_) * 1024 + ic0_                  \
                   + ((sp_ ^ (oc_ & 7)) << 3);                                            \
            gld16(src_, (Wsb) + (size_t)(u_ * 256 + wvb) * 8);                            \
        }                                                                                 \
    } while (0)

    CONV_STAGE(0, &As[0][0], &Ws[0][0]);
    __syncthreads();   // drains vmcnt(0): buf0 staged

    int cur = 0;
    for (int c = 0; c < 144; ++c) {
        if (c + 1 < 144) CONV_STAGE(c + 1, &As[cur ^ 1][0], &Ws[cur ^ 1][0]);
        const unsigned short* Ac = &As[cur][0];
        const unsigned short* Wc = &Ws[cur][0];
#pragma unroll
        for (int kk = 0; kk < 2; kk++) {
            short8 af[4], bfr[2];
#pragma unroll
            for (int mi = 0; mi < 4; mi++) {
                int px = wave_px + mi * 16 + lane16;
                af[mi] = *(const short8*)&Ac[px * 64 + (((kk * 4 + quad) ^ (px & 7)) << 3)];
            }
#pragma unroll
            for (int ni = 0; ni < 2; ni++) {
                int oc = wave_oc + ni * 16 + lane16;
                bfr[ni] = *(const short8*)&Wc[oc * 64 + (((kk * 4 + quad) ^ (oc & 7)) << 3)];
            }
#pragma unroll
            for (int mi = 0; mi < 4; mi++)
#pragma unroll
                for (int ni = 0; ni < 2; ni++)
                    acc[mi][ni] = __builtin_amdgcn_mfma_f32_16x16x32_bf16(
                        af[mi], bfr[ni], acc[mi][ni], 0, 0, 0);
        }
        __syncthreads();   // drains next-buf staging + this-buf reads
        cur ^= 1;
    }
#undef CONV_STAGE

    // epilogue -> pixel-major rpn
#pragma unroll
    for (int ni = 0; ni < 2; ni++) {
        int oc = oct * 64 + wave_oc + ni * 16 + lane16;
        float bias = Bs[oc];
#pragma unroll
        for (int mi = 0; mi < 4; mi++) {
#pragma unroll
            for (int r2 = 0; r2 < 4; r2++) {
                int px = wave_px + mi * 16 + quad * 4 + r2;
                if (px < 120)
                    out[(size_t)(h * 120 + px) * 512 + oc] =
                        f2bf(fmaxf(acc[mi][ni][r2] + bias, 0.f));
            }
        }
    }
}

// ---------------- heads via MFMA: [9120 px][512] @ [54][512]^T -> cls_s, bbox_p ----------------
// grid 72, block 256. Block tile 128 px x 64 oc (54 used), K=512 in 16 chunks.
__global__ __launch_bounds__(256) void heads_mfma_kernel(
    const unsigned short* __restrict__ rpn,   // [9120][512] bf16
    const float* __restrict__ cw, const float* __restrict__ cb,
    const float* __restrict__ bw, const float* __restrict__ bb,
    float* __restrict__ cls_s, float* __restrict__ bbox_p) {
    __shared__ __align__(16) unsigned short As[128 * 42];
    __shared__ __align__(16) unsigned short Ws[64 * 42];
    const int tid = threadIdx.x;
    const int px0 = blockIdx.x * 128;
    const int lane = tid & 63, wv = tid >> 6;
    const int lane16 = lane & 15, quad = lane >> 4;
    const int wave_px = (wv & 1) * 64, wave_oc = (wv >> 1) * 32;

    f32x4 acc[4][2];
#pragma unroll
    for (int mi = 0; mi < 4; mi++)
#pragma unroll
        for (int ni = 0; ni < 2; ni++) acc[mi][ni] = (f32x4){0.f, 0.f, 0.f, 0.f};

    const int wn = tid >> 2, wseg = tid & 3;   // W staging: n, 8-float segment
    const float* wsrc = (wn < 18) ? (cw + (size_t)wn * 512)
                      : (wn < 54) ? (bw + (size_t)(wn - 18) * 512) : nullptr;

    short8 rA[2];
    float4 rw0, rw1;
    {
        int k0 = 0;
#pragma unroll
        for (int u = 0; u < 2; u++) {
            int lid = tid + 256 * u;
            int row = lid >> 2, seg = lid & 3;
            int px = px0 + row;
            rA[u] = (px < NPIX) ? *(const short8*)(rpn + (size_t)px * 512 + k0 + seg * 8)
                                : (short8){0, 0, 0, 0, 0, 0, 0, 0};
        }
        if (wsrc) {
            rw0 = *(const float4*)(wsrc + k0 + wseg * 8);
            rw1 = *(const float4*)(wsrc + k0 + wseg * 8 + 4);
        } else { rw0 = make_float4(0, 0, 0, 0); rw1 = rw0; }
    }
    for (int c = 0; c < 16; ++c) {
        __syncthreads();
#pragma unroll
        for (int u = 0; u < 2; u++) {
            int lid = tid + 256 * u;
            int row = lid >> 2, seg = lid & 3;
            *(short8*)&As[row * 42 + seg * 8] = rA[u];
        }
        {
            short8 wb;
            float* p0 = (float*)&rw0;
            float* p1 = (float*)&rw1;
#pragma unroll
            for (int v = 0; v < 4; v++) { wb[v] = (short)f2bf(p0[v]); wb[4 + v] = (short)f2bf(p1[v]); }
            *(short8*)&Ws[wn * 42 + wseg * 8] = wb;
        }
        if (c + 1 < 16) {
            int k0 = (c + 1) * 32;
#pragma unroll
            for (int u = 0; u < 2; u++) {
                int lid = tid + 256 * u;
                int row = lid >> 2, seg = lid & 3;
                int px = px0 + row;
                rA[u] = (px < NPIX) ? *(const short8*)(rpn + (size_t)px * 512 + k0 + seg * 8)
                                    : (short8){0, 0, 0, 0, 0, 0, 0, 0};
            }
            if (wsrc) {
                rw0 = *(const float4*)(wsrc + k0 + wseg * 8);
                rw1 = *(const float4*)(wsrc + k0 + wseg * 8 + 4);
            }
        }
        __syncthreads();
        short8 af[4], bfr[2];
#pragma unroll
        for (int mi = 0; mi < 4; mi++)
            af[mi] = *(const short8*)&As[(wave_px + mi * 16 + lane16) * 42 + quad * 8];
#pragma unroll
        for (int ni = 0; ni < 2; ni++)
            bfr[ni] = *(const short8*)&Ws[(wave_oc + ni * 16 + lane16) * 42 + quad * 8];
#pragma unroll
        for (int mi = 0; mi < 4; mi++)
#pragma unroll
            for (int ni = 0; ni < 2; ni++)
                acc[mi][ni] = __builtin_amdgcn_mfma_f32_16x16x32_bf16(af[mi], bfr[ni],
                                                                     acc[mi][ni], 0, 0, 0);
    }
#pragma unroll
    for (int ni = 0; ni < 2; ni++) {
        int oc = wave_oc + ni * 16 + lane16;
        float* dst;
        float bias;
        if (oc < 18) { dst = cls_s + (size_t)oc * NPIX; bias = cb[oc]; }
        else if (oc < 54) { dst = bbox_p + (size_t)(oc - 18) * NPIX; bias = bb[oc - 18]; }
        else continue;
#pragma unroll
        for (int mi = 0; mi < 4; mi++) {
            int pxb = px0 + wave_px + mi * 16 + quad * 4;
            if (pxb < NPIX) {
                float4 v = make_float4(acc[mi][ni][0] + bias, acc[mi][ni][1] + bias,
                                       acc[mi][ni][2] + bias, acc[mi][ni][3] + bias);
                *(float4*)(dst + pxb) = v;
            }
        }
    }
}

// ---------------- decode ----------------
__global__ void decode_kernel(const float* __restrict__ cls_s, const float* __restrict__ bbox_p,
                              const float* __restrict__ anchors,
                              unsigned int* __restrict__ keys, float* __restrict__ boxes) {
    int i = blockIdx.x * 256 + threadIdx.x;
    if (i >= NANCH) return;
    int pix = i / AA;
    int a = i - pix * AA;
    float s0 = cls_s[(size_t)a * NPIX + pix];
    float s1 = cls_s[(size_t)(AA + a) * NPIX + pix];
    float d = s1 - s0;
    unsigned int u = __float_as_uint(d);
    keys[i] = (u & 0x80000000u) ? ~u : (u | 0x80000000u);

    float dx = bbox_p[(size_t)(4 * a + 0) * NPIX + pix];
    float dy = bbox_p[(size_t)(4 * a + 1) * NPIX + pix];
    float dw = bbox_p[(size_t)(4 * a + 2) * NPIX + pix];
    float dh = bbox_p[(size_t)(4 * a + 3) * NPIX + pix];
    float ax1 = anchors[(size_t)i * 4 + 0];
    float ay1 = anchors[(size_t)i * 4 + 1];
    float ax2 = anchors[(size_t)i * 4 + 2];
    float ay2 = anchors[(size_t)i * 4 + 3];
    float aw = ax2 - ax1 + 1.f;
    float ah = ay2 - ay1 + 1.f;
    float acx = ax1 + 0.5f * aw;
    float acy = ay1 + 0.5f * ah;
    float pcx = dx * aw + acx;
    float pcy = dy * ah + acy;
    float pw = __expf(dw) * aw;
    float ph = __expf(dh) * ah;
    const float XMAX = 16.f * WW - 1.f;
    const float YMAX = 16.f * HH - 1.f;
    boxes[(size_t)i * 4 + 0] = fminf(fmaxf(pcx - 0.5f * pw, 0.f), XMAX);
    boxes[(size_t)i * 4 + 1] = fminf(fmaxf(pcy - 0.5f * ph, 0.f), YMAX);
    boxes[(size_t)i * 4 + 2] = fminf(fmaxf(pcx + 0.5f * pw, 0.f), XMAX);
    boxes[(size_t)i * 4 + 3] = fminf(fmaxf(pcy + 0.5f * ph, 0.f), YMAX);
}

// ---------------- exact top-k ----------------
__global__ __launch_bounds__(1024) void topk_kernel(const unsigned int* __restrict__ keys,
                                                    int* __restrict__ top_idx) {
    const int N = NANCH, K = TOPN;
    __shared__ unsigned int s_prefix;
    __shared__ int s_k;
    __shared__ unsigned int hist[256];
    __shared__ int s_ngt, s_neq;
    __shared__ unsigned long long s_sel[512];
    __shared__ int s_eq[1024];
    int tid = threadIdx.x;
    if (tid == 0) { s_prefix = 0u; s_k = K; }
    __syncthreads();

    for (int d = 3; d >= 0; --d) {
        if (tid < 256) hist[tid] = 0u;
        __syncthreads();
        unsigned int pfx = s_prefix;
        unsigned int maskHigh = (d == 3) ? 0u : ~((1u << ((d + 1) * 8)) - 1u);
        int shift = d * 8;
        for (int i = tid; i < N; i += 1024) {
            unsigned int k = keys[i];
            if ((k & maskHigh) == (pfx & maskHigh))
                atomicAdd(&hist[(k >> shift) & 255u], 1u);
        }
        __syncthreads();
        if (tid == 0) {
            int kk = s_k;
            int cum = 0;
            unsigned int sel = 0;
            for (int v = 255; v >= 0; v--) {
                int hcnt = (int)hist[v];
                if (cum + hcnt >= kk) { sel = (unsigned int)v; s_k = kk - cum; break; }
                cum += hcnt;
            }
            s_prefix = pfx | (sel << shift);
        }
        __syncthreads();
    }
    unsigned int T = s_prefix;
    int krem = s_k;
    if (tid == 0) { s_ngt = 0; s_neq = 0; }
    __syncthreads();
    for (int i = tid; i < N; i += 1024) {
        unsigned int k = keys[i];
        if (k > T) {
            int p = atomicAdd(&s_ngt, 1);
            if (p < 512)
                s_sel[p] = ((unsigned long long)k << 32) | (unsigned int)(~(unsigned int)i);
        } else if (k == T) {
            int p = atomicAdd(&s_neq, 1);
            if (p < 1024) s_eq[p] = i;
        }
    }
    __syncthreads();
    int ngt = min(s_ngt, 512);
    int neq = min(s_neq, 1024);
    for (int e = tid; e < neq; e += 1024) {
        int idx = s_eq[e];
        int rank = 0;
        for (int j = 0; j < neq; j++)
            if (s_eq[j] < idx) rank++;
        if (rank < krem && ngt + rank < 512)
            s_sel[ngt + rank] = ((unsigned long long)T << 32) | (unsigned int)(~(unsigned int)idx);
    }
    __syncthreads();
    for (int p = K + tid; p < 512; p += 1024) s_sel[p] = 0ULL;
    __syncthreads();
    for (unsigned int k2 = 2; k2 <= 512; k2 <<= 1) {
        for (unsigned int j = k2 >> 1; j > 0; j >>= 1) {
            if (tid < 512) {
                int i = tid;
                int ixj = i ^ (int)j;
                if (ixj > i) {
                    unsigned long long a = s_sel[i], cc = s_sel[ixj];
                    bool up = ((i & k2) == 0);
                    if (up ? (a > cc) : (a < cc)) { s_sel[i] = cc; s_sel[ixj] = a; }
                }
            }
            __syncthreads();
        }
    }
    if (tid < K)
        top_idx[tid] = (int)(~(unsigned int)(s_sel[511 - tid] & 0xFFFFFFFFull));
}

// ---------------- roi align from Fpix -> pooled (n,q,c) bf16 ----------------
__global__ __launch_bounds__(256) void roialign_kernel(
    const unsigned short* __restrict__ Fpix, const float* __restrict__ boxes,
    const int* __restrict__ top_idx, unsigned short* __restrict__ pooled) {
    int n = blockIdx.x;
    int q = blockIdx.y;
    int ph = q / 7, pw = q - ph * 7;
    int bi = top_idx[n];
    float x1 = boxes[(size_t)bi * 4 + 0] * (1.f / 16.f);
    float y1 = boxes[(size_t)bi * 4 + 1] * (1.f / 16.f);
    float x2 = boxes[(size_t)bi * 4 + 2] * (1.f / 16.f);
    float y2 = boxes[(size_t)bi * 4 + 3] * (1.f / 16.f);
    float gx = (pw + 0.5f) / 7.f;
    float gy = (ph + 0.5f) / 7.f;
    float xs = fminf(fmaxf(x1 + (x2 - x1) * gx, 0.f), (float)(WW - 1));
    float ys = fminf(fmaxf(y1 + (y2 - y1) * gy, 0.f), (float)(HH - 1));
    float x0f = floorf(xs), y0f = floorf(ys);
    int x0 = (int)x0f, y0 = (int)y0f;
    int x1i = min(x0 + 1, WW - 1);
    int y1i = min(y0 + 1, HH - 1);
    float wx = xs - x0f, wy = ys - y0f;
    float w00 = (1.f - wy) * (1.f - wx), w01 = (1.f - wy) * wx;
    float w10 = wy * (1.f - wx), w11 = wy * wx;
    const unsigned short* r00 = Fpix + (size_t)((y0 + 1) * PW + x0 + 1) * 1024;
    const unsigned short* r01 = Fpix + (size_t)((y0 + 1) * PW + x1i + 1) * 1024;
    const unsigned short* r10 = Fpix + (size_t)((y1i + 1) * PW + x0 + 1) * 1024;
    const unsigned short* r11 = Fpix + (size_t)((y1i + 1) * PW + x1i + 1) * 1024;
    unsigned short* dst = pooled + (size_t)n * KFC + (size_t)q * CIN;
    int c = threadIdx.x * 4;
    ushort4 a = *(const ushort4*)(r00 + c);
    ushort4 b = *(const ushort4*)(r01 + c);
    ushort4 cc = *(const ushort4*)(r10 + c);
    ushort4 d = *(const ushort4*)(r11 + c);
    ushort4 o;
    o.x = f2bf(w00 * bf2f(a.x) + w01 * bf2f(b.x) + w10 * bf2f(cc.x) + w11 * bf2f(d.x));
    o.y = f2bf(w00 * bf2f(a.y) + w01 * bf2f(b.y) + w10 * bf2f(cc.y) + w11 * bf2f(d.y));
    o.z = f2bf(w00 * bf2f(a.z) + w01 * bf2f(b.z) + w10 * bf2f(cc.z) + w11 * bf2f(d.z));
    o.w = f2bf(w00 * bf2f(a.w) + w01 * bf2f(b.w) + w10 * bf2f(cc.w) + w11 * bf2f(d.w));
    *(ushort4*)(dst + c) = o;
}

// ---------------- FC GEMM via MFMA: fc7 += pooled(300x50176 bf16) @ fc_w(fp32->bf16) ----------
// grid 256: kz = b&7 (XCD-affine), j-tile = b>>3 (64 cols). Block: 320 px x 64 col.
__global__ __launch_bounds__(256) void fc_mfma_kernel(
    const unsigned short* __restrict__ pooled, const float* __restrict__ fc_w,
    float* __restrict__ fc7) {
    __shared__ __align__(16) unsigned short As[320 * 42];
    __shared__ __align__(16) unsigned short Ws[64 * 42];
    const int tid = threadIdx.x;
    const int b = blockIdx.x;
    const int kz = b & 7;
    const int j0 = (b >> 3) * 64;
    const int lane = tid & 63, wv = tid >> 6;
    const int lane16 = lane & 15, quad = lane >> 4;
    const int m0 = wv * 80;
    const int kbase = kz * 6272;
    const int g = tid >> 4;              // W staging: krow pair 2g, 2g+1
    const int col4 = (tid & 15) * 4;

    f32x4 acc[5][4];
#pragma unroll
    for (int mi = 0; mi < 5; mi++)
#pragma unroll
        for (int ni = 0; ni < 4; ni++) acc[mi][ni] = (f32x4){0.f, 0.f, 0.f, 0.f};

    short8 rA[5];
    float4 rW0[2], rW1[2];

#define LOAD_A(cIdx)                                                              \
    {                                                                             \
        int k0_ = kbase + (cIdx) * 32;                                            \
        _Pragma("unroll")                                                         \
        for (int i = 0; i < 5; i++) {                                             \
            int lid = tid + 256 * i;                                              \
            int row = lid >> 2, seg = lid & 3;                                    \
            rA[i] = (row < TOPN)                                                  \
                  ? *(const short8*)(pooled + (size_t)row * KFC + k0_ + seg * 8)  \
                  : (short8){0, 0, 0, 0, 0, 0, 0, 0};                             \
        }                                                                         \
    }
#define LOAD_W(cIdx, dst)                                                         \
    {                                                                             \
        int k0_ = kbase + (cIdx) * 32;                                            \
        int q_ = k0_ >> 10, c0_ = k0_ & 1023;                                     \
        _Pragma("unroll")                                                         \
        for (int u = 0; u < 2; u++)                                               \
            dst[u] = *(const float4*)(fc_w +                                      \
                ((size_t)(c0_ + 2 * g + u) * 49 + q_) * FCDIM + j0 + col4);       \
    }

    LOAD_A(0);
    LOAD_W(0, rW0);
    LOAD_W(1, rW1);

    for (int c = 0; c < 196; ++c) {
        __syncthreads();
#pragma unroll
        for (int i = 0; i < 5; i++) {
            int lid = tid + 256 * i;
            int row = lid >> 2, seg = lid & 3;
            *(short8*)&As[row * 42 + seg * 8] = rA[i];
        }
        {
            float* p0 = (float*)&rW0[0];
            float* p1 = (float*)&rW0[1];
#pragma unroll
            for (int v = 0; v < 4; v++) {
                unsigned int pk = (unsigned int)f2bf(p0[v]) | ((unsigned int)f2bf(p1[v]) << 16);
                *(unsigned int*)&Ws[(col4 + v) * 42 + 2 * g] = pk;
            }
        }
        if (c + 1 < 196) LOAD_A(c + 1);
        rW0[0] = rW1[0]; rW0[1] = rW1[1];
        if (c + 2 < 196) LOAD_W(c + 2, rW1);
        __syncthreads();
        short8 af[5], bfr[4];
#pragma unroll
        for (int mi = 0; mi < 5; mi++)
            af[mi] = *(const short8*)&As[(m0 + mi * 16 + lane16) * 42 + quad * 8];
#pragma unroll
        for (int ni = 0; ni < 4; ni++)
            bfr[ni] = *(const short8*)&Ws[(ni * 16 + lane16) * 42 + quad * 8];
#pragma unroll
        for (int mi = 0; mi < 5; mi++)
#pragma unroll
            for (int ni = 0; ni < 4; ni++)
                acc[mi][ni] = __builtin_amdgcn_mfma_f32_16x16x32_bf16(af[mi], bfr[ni],
                                                                     acc[mi][ni], 0, 0, 0);
    }
#undef LOAD_A
#undef LOAD_W
#pragma unroll
    for (int mi = 0; mi < 5; mi++) {
#pragma unroll
        for (int r = 0; r < 4; r++) {
            int m = m0 + mi * 16 + quad * 4 + r;
            if (m < TOPN) {
#pragma unroll
                for (int ni = 0; ni < 4; ni++)
                    atomicAdd(&fc7[(size_t)m * FCDIM + j0 + ni * 16 + lane16], acc[mi][ni][r]);
            }
        }
    }
}

// ---------------- fc7 bias + relu ----------------
__global__ void bias_relu_kernel(float* __restrict__ fc7, const float* __restrict__ fc_b) {
    int i = blockIdx.x * 256 + threadIdx.x;
    if (i < TOPN * FCDIM)
        fc7[i] = fmaxf(fc7[i] + fc_b[i & (FCDIM - 1)], 0.f);
}

// ---------------- head GEMMs ----------------
__global__ __launch_bounds__(128) void head_gemm_kernel(
    const float* __restrict__ fc7,
    const float* __restrict__ cw, const float* __restrict__ cb,
    const float* __restrict__ bw, const float* __restrict__ bb,
    float* __restrict__ cls_score, float* __restrict__ bbox_pred) {
    int n = blockIdx.x;
    __shared__ float row[FCDIM];
    for (int k = threadIdx.x; k < FCDIM; k += 128) row[k] = fc7[(size_t)n * FCDIM + k];
    __syncthreads();
    int t = threadIdx.x;
    if (t < 21) {
        float acc = 0.f;
        for (int k = 0; k < FCDIM; k += 4) {
#pragma unroll
            for (int u = 0; u < 4; u++) acc += row[k + u] * cw[(size_t)(k + u) * 21 + t];
        }
        cls_score[n * 21 + t] = acc + cb[t];
    } else if (t < 105) {
        int oc = t - 21;
        float acc = 0.f;
        for (int k = 0; k < FCDIM; k += 4) {
#pragma unroll
            for (int u = 0; u < 4; u++) acc += row[k + u] * bw[(size_t)(k + u) * 84 + oc];
        }
        bbox_pred[n * 84 + oc] = acc + bb[oc];
    }
}

// ---------------- losses ----------------
__device__ __forceinline__ void block_atomic_acc(float v, float* dst) {
    for (int o = 32; o > 0; o >>= 1) v += __shfl_down(v, o);
    if ((threadIdx.x & 63) == 0) atomicAdd(dst, v);
}

__global__ void loss_rpn_ce_kernel(const float* __restrict__ cls_s,
                                   const int* __restrict__ labels, float* __restrict__ acc) {
    int i = blockIdx.x * 256 + threadIdx.x;
    float ce = 0.f, cnt = 0.f;
    if (i < NANCH) {
        int lab = labels[i];
        if (lab != -1) {
            int a = i / NPIX, pix = i - a * NPIX;
            float s0 = cls_s[(size_t)a * NPIX + pix];
            float s1 = cls_s[(size_t)(AA + a) * NPIX + pix];
            float m = fmaxf(s0, s1);
            float lse = m + logf(expf(s0 - m) + expf(s1 - m));
            ce = lse - (lab ? s1 : s0);
            cnt = 1.f;
        }
    }
    block_atomic_acc(ce, &acc[0]);
    block_atomic_acc(cnt, &acc[1]);
}

__global__ void loss_rpn_bbox_kernel(const float* __restrict__ bbox_p,
                                     const float* __restrict__ tgt,
                                     const float* __restrict__ biw,
                                     const float* __restrict__ bow, float* __restrict__ acc) {
    int e = blockIdx.x * 256 + threadIdx.x;
    float contrib = 0.f;
    if (e < NPIX * 36) {
        int pix = e / 36, c = e - pix * 36;
        float pred = bbox_p[(size_t)c * NPIX + pix];
        float d = biw[e] * (pred - tgt[e]);
        float ad = fabsf(d);
        float l = (ad < (1.f / 9.f)) ? d * d * 4.5f : ad - (1.f / 18.f);
        contrib = bow[e] * l;
    }
    block_atomic_acc(contrib, &acc[2]);
}

__global__ void loss_cls_kernel(const float* __restrict__ cls_score,
                                const int* __restrict__ labels, float* __restrict__ acc) {
    int n = blockIdx.x * 256 + threadIdx.x;
    float ce = 0.f;
    if (n < TOPN) {
        const float* lg = cls_score + n * 21;
        float m = lg[0];
        for (int j = 1; j < 21; j++) m = fmaxf(m, lg[j]);
        float s = 0.f;
        for (int j = 0; j < 21; j++) s += expf(lg[j] - m);
        ce = m + logf(s) - lg[labels[n]];
    }
    block_atomic_acc(ce, &acc[3]);
}

__global__ void loss_roi_bbox_kernel(const float* __restrict__ bbox_pred,
                                     const float* __restrict__ tgt,
                                     const float* __restrict__ biw,
                                     const float* __restrict__ bow, float* __restrict__ acc) {
    int e = blockIdx.x * 256 + threadIdx.x;
    float contrib = 0.f;
    if (e < TOPN * 84) {
        float d = biw[e] * (bbox_pred[e] - tgt[e]);
        float ad = fabsf(d);
        float l = (ad < 1.f) ? 0.5f * d * d : ad - 0.5f;
        contrib = bow[e] * l;
    }
    block_atomic_acc(contrib, &acc[4]);
}

__global__ void finalize_kernel(const float* __restrict__ acc, float* __restrict__ out) {
    out[0] = acc[0] / fmaxf(acc[1], 1.f) + acc[2]
           + acc[3] * (1.f / TOPN) + acc[4] * (1.f / TOPN);
}

// ---------------- launch ----------------
extern "C" void kernel_launch(void* const* d_in, const int* in_sizes, int n_in,
                              void* d_out, int out_size, void* d_ws, size_t ws_size,
                              hipStream_t stream) {
    const float* net_conv   = (const float*)d_in[0];
    const float* rpn_w      = (const float*)d_in[1];
    const float* rpn_b      = (const float*)d_in[2];
    const float* rpn_cls_w  = (const float*)d_in[3];
    const float* rpn_cls_b  = (const float*)d_in[4];
    const float* rpn_bbox_w = (const float*)d_in[5];
    const float* rpn_bbox_b = (const float*)d_in[6];
    const float* fc_w       = (const float*)d_in[7];
    const float* fc_b       = (const float*)d_in[8];
    const float* cls_w      = (const float*)d_in[9];
    const float* cls_b      = (const float*)d_in[10];
    const float* bbox_w     = (const float*)d_in[11];
    const float* bbox_b     = (const float*)d_in[12];
    const float* anchors    = (const float*)d_in[13];
    const float* rpn_bt     = (const float*)d_in[14];
    const float* rpn_biw    = (const float*)d_in[15];
    const float* rpn_bow    = (const float*)d_in[16];
    const float* roi_bt     = (const float*)d_in[17];
    const float* roi_biw    = (const float*)d_in[18];
    const float* roi_bow    = (const float*)d_in[19];
    const int* rpn_labels   = (const int*)d_in[20];
    const int* roi_labels   = (const int*)d_in[21];

    char* base = (char*)d_ws;
    unsigned short* Fpix = (unsigned short*)base;
    const size_t FPIX_BYTES = (size_t)FPIX_ROWS * 1024 * 2;  // 20,463,616
    unsigned short* Wb = (unsigned short*)(base + FPIX_BYTES);
    unsigned short* rpn = (unsigned short*)(base + 29900800);  // [9120][512] bf16
    unsigned short* pooled = (unsigned short*)(base + FPIX_BYTES);
    size_t off = 50569216;
    float* cls_s = (float*)(base + off);      off += 656640;
    float* bbox_p = (float*)(base + off);     off += 1313280;
    unsigned int* keys = (unsigned int*)(base + off); off += 328448;
    float* boxes = (float*)(base + off);      off += 1313280;
    int* top_idx = (int*)(base + off);        off += 1280;
    float* cls_score = (float*)(base + off);  off += 25600;
    float* bbox_pred = (float*)(base + off);  off += 100864;
    float* fc7 = (float*)(base + off);        off += 2457600;
    float* accum = (float*)(base + off);      off += 256;
    float* out = (float*)d_out;

    zero4_kernel<<<(int)((FPIX_BYTES / 16 + 255) / 256), 256, 0, stream>>>((float4*)Fpix,
                                                                           (int)(FPIX_BYTES / 16));
    fpix_fill_kernel<<<dim3(143, 16), 256, 0, stream>>>(net_conv, Fpix);
    wb_fill_kernel<<<2048, 256, 0, stream>>>(rpn_w, Wb);
    zero_kernel<<<2401, 256, 0, stream>>>(fc7, TOPN * FCDIM + 16);

    conv_mfma_kernel<<<640, 256, 0, stream>>>(Fpix, Wb, rpn_b, rpn);
    heads_mfma_kernel<<<72, 256, 0, stream>>>(rpn, rpn_cls_w, rpn_cls_b,
                                              rpn_bbox_w, rpn_bbox_b, cls_s, bbox_p);
    decode_kernel<<<(NANCH + 255) / 256, 256, 0, stream>>>(cls_s, bbox_p, anchors, keys, boxes);
    topk_kernel<<<1, 1024, 0, stream>>>(keys, top_idx);
    roialign_kernel<<<dim3(300, 49), 256, 0, stream>>>(Fpix, boxes, top_idx, pooled);
    fc_mfma_kernel<<<256, 256, 0, stream>>>(pooled, fc_w, fc7);
    bias_relu_kernel<<<(TOPN * FCDIM + 255) / 256, 256, 0, stream>>>(fc7, fc_b);
    head_gemm_kernel<<<300, 128, 0, stream>>>(fc7, cls_w, cls_b, bbox_w, bbox_b,
                                              cls_score, bbox_pred);
    loss_rpn_ce_kernel<<<(NANCH + 255) / 256, 256, 0, stream>>>(cls_s, rpn_labels, accum);
    loss_rpn_bbox_kernel<<<(NPIX * 36 + 255) / 256, 256, 0, stream>>>(bbox_p, rpn_bt,
                                                                      rpn_biw, rpn_bow, accum);
    loss_cls_kernel<<<2, 256, 0, stream>>>(cls_score, roi_labels, accum);
    loss_roi_bbox_kernel<<<(TOPN * 84 + 255) / 256, 256, 0, stream>>>(bbox_pred, roi_bt,
                                                                      roi_biw, roi_bow, accum);
    finalize_kernel<<<1, 1, 0, stream>>>(accum, out);
}

// Round 3
// 1219.508 us; speedup vs baseline: 1.2162x; 1.0431x over previous
//
#include <hip/hip_runtime.h>
#include <cstddef>

#define HH 76
#define WW 120
#define NPIX (HH*WW)          // 9120
#define AA 9
#define NANCH (NPIX*AA)       // 82080
#define TOPN 300
#define CIN 1024
#define CMID 512
#define FCDIM 2048
#define KFC (CIN*49)          // 50176
#define PW 128
#define PROWS (78*128)        // 9984 padded pixel rows
#define FPIX_ROWS (PROWS + 8)

typedef __attribute__((ext_vector_type(8))) short short8;
typedef __attribute__((ext_vector_type(4))) float f32x4;

__device__ __forceinline__ float bf2f(unsigned short h) {
    return __uint_as_float(((unsigned int)h) << 16);
}
__device__ __forceinline__ unsigned short f2bf(float f) {
    unsigned int u = __float_as_uint(f);
    unsigned int r = (u + 0x7FFFu + ((u >> 16) & 1u)) >> 16;
    return (unsigned short)r;
}
// packed f32x2 -> bf16x2 (RNE), single instruction
__device__ __forceinline__ unsigned int cvt_pk_bf16(float lo, float hi) {
    unsigned int r;
    asm("v_cvt_pk_bf16_f32 %0, %1, %2" : "=v"(r) : "v"(lo), "v"(hi));
    return r;
}

// async global->LDS, 16B per lane. LDS dest = wave-uniform base + lane*16.
__device__ __forceinline__ void gld16(const unsigned short* g, unsigned short* l) {
    __builtin_amdgcn_global_load_lds(
        (const __attribute__((address_space(1))) unsigned int*)(g),
        (__attribute__((address_space(3))) unsigned int*)(l),
        16, 0, 0);
}

// ---------------- zero init ----------------
__global__ void zero_kernel(float* __restrict__ p, int n) {
    int i = blockIdx.x * 256 + threadIdx.x;
    if (i < n) p[i] = 0.f;
}
__global__ void zero4_kernel(float4* __restrict__ p, int n4) {
    int i = blockIdx.x * 256 + threadIdx.x;
    if (i < n4) p[i] = make_float4(0.f, 0.f, 0.f, 0.f);
}

// ---------------- Fpix fill: [ic][px] fp32 -> [padded px][ic] bf16 ----------------
__global__ __launch_bounds__(256) void fpix_fill_kernel(const float* __restrict__ F,
                                                        unsigned short* __restrict__ Fpix) {
    __shared__ float s[64][65];
    int px0 = blockIdx.x * 64, ic0 = blockIdx.y * 64;
    int t = threadIdx.x;
#pragma unroll 4
    for (int i = 0; i < 16; i++) {
        int ic = (t >> 6) + i * 4;
        int px = px0 + (t & 63);
        float v = (px < NPIX) ? F[(size_t)(ic0 + ic) * NPIX + px] : 0.f;
        s[t & 63][ic] = v;
    }
    __syncthreads();
    int pxl = t >> 2;
    int px = px0 + pxl;
    if (px < NPIX) {
        int h = px / 120, w = px - h * 120;
        size_t prow = (size_t)(h + 1) * PW + (w + 1);
        unsigned short* dst = Fpix + prow * 1024 + ic0 + (t & 3) * 16;
#pragma unroll
        for (int u = 0; u < 16; u++) dst[u] = f2bf(s[pxl][(t & 3) * 16 + u]);
    }
}

// ---------------- Wb fill: [ocic][9] fp32 -> [tap][ocic] bf16 (LDS transpose) ----------------
__global__ __launch_bounds__(256) void wb_fill_kernel(const float* __restrict__ Wsrc,
                                                      unsigned short* __restrict__ Wb) {
    __shared__ float s[2304];
    int r0 = blockIdx.x * 256;
    int t = threadIdx.x;
    const float4* src4 = (const float4*)(Wsrc + (size_t)r0 * 9);
#pragma unroll
    for (int i = 0; i < 3; i++) {
        int idx = t + 256 * i;
        if (idx < 576) *(float4*)&s[idx * 4] = src4[idx];
    }
    __syncthreads();
#pragma unroll
    for (int tap = 0; tap < 9; tap++)
        Wb[(size_t)tap * 524288 + r0 + t] = f2bf(s[t * 9 + tap]);
}

// ---------------- conv 3x3 via MFMA implicit GEMM -> rpn pixel-major [px][512] ----------------
// v4: counted-vmcnt pipeline (T4). Per iter: STAGE(c+1) issue -> s_waitcnt vmcnt(6)
// (waits only stage(c), issued a full iter earlier; next-tile loads stay in flight) ->
// raw barrier -> compute -> lgkmcnt(0) -> raw barrier. No vmcnt(0) drain in the loop.
// Keeps v3's XOR-swizzled LDS (T2) and XCD-affine h-chunk mapping (T1).
__global__ __launch_bounds__(256) void conv_mfma_kernel(
    const unsigned short* __restrict__ Fpix,
    const unsigned short* __restrict__ Wb,
    const float* __restrict__ Bs,
    unsigned short* __restrict__ out) {       // [9120][512] bf16
    __shared__ __align__(16) unsigned short As[2][128 * 64];  // [buf][px][64 ic-shorts]
    __shared__ __align__(16) unsigned short Ws[2][64 * 64];   // [buf][oc][64 ic-shorts]
    const int tid = threadIdx.x;
    const int flat = blockIdx.x;
    const int xcd = flat & 7;
    const int r = flat >> 3;           // 0..79
    const int oct = r & 7;
    const int h = xcd * 10 + (r >> 3); // h-chunk per XCD
    if (h >= HH) return;
    const int lane = tid & 63, wv = tid >> 6;
    const int lane16 = lane & 15, quad = lane >> 4;
    const int wave_px = (wv & 1) * 64, wave_oc = (wv >> 1) * 32;
    const int wvb = wv * 64;           // wave slot base for staging

    f32x4 acc[4][2];
#pragma unroll
    for (int mi = 0; mi < 4; mi++)
#pragma unroll
        for (int ni = 0; ni < 2; ni++) acc[mi][ni] = (f32x4){0.f, 0.f, 0.f, 0.f};

#define CONV_STAGE(cc, Ab, Wsb)                                                           \
    do {                                                                                  \
        int tap_ = (cc) >> 4;                                                             \
        int ic0_ = ((cc) & 15) << 6;                                                      \
        int dh_ = (tap_ * 11) >> 5;                                                       \
        int dw_ = tap_ - dh_ * 3;                                                         \
        _Pragma("unroll")                                                                 \
        for (int u_ = 0; u_ < 4; u_++) {                                                  \
            int slot_ = u_ * 256 + tid;                                                   \
            int px_ = slot_ >> 3, sp_ = slot_ & 7;                                        \
            const unsigned short* src_ =                                                  \
                Fpix + (size_t)((h + dh_) * PW + px_ + dw_) * 1024 + ic0_                 \
                     + ((sp_ ^ (px_ & 7)) << 3);                                          \
            gld16(src_, (Ab) + (size_t)(u_ * 256 + wvb) * 8);                             \
        }                                                                                 \
        _Pragma("unroll")                                                                 \
        for (int u_ = 0; u_ < 2; u_++) {                                                  \
            int slot_ = u_ * 256 + tid;                                                   \
            int oc_ = slot_ >> 3, sp_ = slot_ & 7;                                        \
            const unsigned short* src_ =                                                  \
                Wb + (size_t)(tap_ * 512 + oct * 64 + oc_) * 1024 + ic0_                  \
                   + ((sp_ ^ (oc_ & 7)) << 3);                                            \
            gld16(src_, (Wsb) + (size_t)(u_ * 256 + wvb) * 8);                            \
        }                                                                                 \
    } while (0)

    CONV_STAGE(0, &As[0][0], &Ws[0][0]);

    int cur = 0;
    for (int c = 0; c < 144; ++c) {
        if (c + 1 < 144) {
            CONV_STAGE(c + 1, &As[cur ^ 1][0], &Ws[cur ^ 1][0]);
            asm volatile("s_waitcnt vmcnt(6)" ::: "memory");  // stage(c) landed; 6 in flight
        } else {
            asm volatile("s_waitcnt vmcnt(0)" ::: "memory");  // final tile
        }
        __builtin_amdgcn_s_barrier();        // all waves' stage(c) visible
        asm volatile("" ::: "memory");       // pin ds_reads below the barrier
        const unsigned short* Ac = &As[cur][0];
        const unsigned short* Wc = &Ws[cur][0];
#pragma unroll
        for (int kk = 0; kk < 2; kk++) {
            short8 af[4], bfr[2];
#pragma unroll
            for (int mi = 0; mi < 4; mi++) {
                int px = wave_px + mi * 16 + lane16;
                af[mi] = *(const short8*)&Ac[px * 64 + (((kk * 4 + quad) ^ (px & 7)) << 3)];
            }
#pragma unroll
            for (int ni = 0; ni < 2; ni++) {
                int oc = wave_oc + ni * 16 + lane16;
                bfr[ni] = *(const short8*)&Wc[oc * 64 + (((kk * 4 + quad) ^ (oc & 7)) << 3)];
            }
#pragma unroll
            for (int mi = 0; mi < 4; mi++)
#pragma unroll
                for (int ni = 0; ni < 2; ni++)
                    acc[mi][ni] = __builtin_amdgcn_mfma_f32_16x16x32_bf16(
                        af[mi], bfr[ni], acc[mi][ni], 0, 0, 0);
        }
        asm volatile("s_waitcnt lgkmcnt(0)" ::: "memory");  // all LDS reads retired
        __builtin_amdgcn_s_barrier();        // safe to overwrite buf[cur] next iter
        cur ^= 1;
    }
#undef CONV_STAGE

    // epilogue -> pixel-major rpn
#pragma unroll
    for (int ni = 0; ni < 2; ni++) {
        int oc = oct * 64 + wave_oc + ni * 16 + lane16;
        float bias = Bs[oc];
#pragma unroll
        for (int mi = 0; mi < 4; mi++) {
#pragma unroll
            for (int r2 = 0; r2 < 4; r2++) {
                int px = wave_px + mi * 16 + quad * 4 + r2;
                if (px < 120)
                    out[(size_t)(h * 120 + px) * 512 + oc] =
                        f2bf(fmaxf(acc[mi][ni][r2] + bias, 0.f));
            }
        }
    }
}

// ---------------- heads via MFMA: [9120 px][512] @ [54][512]^T -> cls_s, bbox_p ----------------
__global__ __launch_bounds__(256) void heads_mfma_kernel(
    const unsigned short* __restrict__ rpn,   // [9120][512] bf16
    const float* __restrict__ cw, const float* __restrict__ cb,
    const float* __restrict__ bw, const float* __restrict__ bb,
    float* __restrict__ cls_s, float* __restrict__ bbox_p) {
    __shared__ __align__(16) unsigned short As[128 * 42];
    __shared__ __align__(16) unsigned short Ws[64 * 42];
    const int tid = threadIdx.x;
    const int px0 = blockIdx.x * 128;
    const int lane = tid & 63, wv = tid >> 6;
    const int lane16 = lane & 15, quad = lane >> 4;
    const int wave_px = (wv & 1) * 64, wave_oc = (wv >> 1) * 32;

    f32x4 acc[4][2];
#pragma unroll
    for (int mi = 0; mi < 4; mi++)
#pragma unroll
        for (int ni = 0; ni < 2; ni++) acc[mi][ni] = (f32x4){0.f, 0.f, 0.f, 0.f};

    const int wn = tid >> 2, wseg = tid & 3;   // W staging: n, 8-float segment
    const float* wsrc = (wn < 18) ? (cw + (size_t)wn * 512)
                      : (wn < 54) ? (bw + (size_t)(wn - 18) * 512) : nullptr;

    short8 rA[2];
    float4 rw0, rw1;
    {
        int k0 = 0;
#pragma unroll
        for (int u = 0; u < 2; u++) {
            int lid = tid + 256 * u;
            int row = lid >> 2, seg = lid & 3;
            int px = px0 + row;
            rA[u] = (px < NPIX) ? *(const short8*)(rpn + (size_t)px * 512 + k0 + seg * 8)
                                : (short8){0, 0, 0, 0, 0, 0, 0, 0};
        }
        if (wsrc) {
            rw0 = *(const float4*)(wsrc + k0 + wseg * 8);
            rw1 = *(const float4*)(wsrc + k0 + wseg * 8 + 4);
        } else { rw0 = make_float4(0, 0, 0, 0); rw1 = rw0; }
    }
    for (int c = 0; c < 16; ++c) {
        __syncthreads();
#pragma unroll
        for (int u = 0; u < 2; u++) {
            int lid = tid + 256 * u;
            int row = lid >> 2, seg = lid & 3;
            *(short8*)&As[row * 42 + seg * 8] = rA[u];
        }
        {
            unsigned int* wp = (unsigned int*)&Ws[wn * 42 + wseg * 8];
            wp[0] = cvt_pk_bf16(rw0.x, rw0.y);
            wp[1] = cvt_pk_bf16(rw0.z, rw0.w);
            wp[2] = cvt_pk_bf16(rw1.x, rw1.y);
            wp[3] = cvt_pk_bf16(rw1.z, rw1.w);
        }
        if (c + 1 < 16) {
            int k0 = (c + 1) * 32;
#pragma unroll
            for (int u = 0; u < 2; u++) {
                int lid = tid + 256 * u;
                int row = lid >> 2, seg = lid & 3;
                int px = px0 + row;
                rA[u] = (px < NPIX) ? *(const short8*)(rpn + (size_t)px * 512 + k0 + seg * 8)
                                    : (short8){0, 0, 0, 0, 0, 0, 0, 0};
            }
            if (wsrc) {
                rw0 = *(const float4*)(wsrc + k0 + wseg * 8);
                rw1 = *(const float4*)(wsrc + k0 + wseg * 8 + 4);
            }
        }
        __syncthreads();
        short8 af[4], bfr[2];
#pragma unroll
        for (int mi = 0; mi < 4; mi++)
            af[mi] = *(const short8*)&As[(wave_px + mi * 16 + lane16) * 42 + quad * 8];
#pragma unroll
        for (int ni = 0; ni < 2; ni++)
            bfr[ni] = *(const short8*)&Ws[(wave_oc + ni * 16 + lane16) * 42 + quad * 8];
#pragma unroll
        for (int mi = 0; mi < 4; mi++)
#pragma unroll
            for (int ni = 0; ni < 2; ni++)
                acc[mi][ni] = __builtin_amdgcn_mfma_f32_16x16x32_bf16(af[mi], bfr[ni],
                                                                     acc[mi][ni], 0, 0, 0);
    }
#pragma unroll
    for (int ni = 0; ni < 2; ni++) {
        int oc = wave_oc + ni * 16 + lane16;
        float* dst;
        float bias;
        if (oc < 18) { dst = cls_s + (size_t)oc * NPIX; bias = cb[oc]; }
        else if (oc < 54) { dst = bbox_p + (size_t)(oc - 18) * NPIX; bias = bb[oc - 18]; }
        else continue;
#pragma unroll
        for (int mi = 0; mi < 4; mi++) {
            int pxb = px0 + wave_px + mi * 16 + quad * 4;
            if (pxb < NPIX) {
                float4 v = make_float4(acc[mi][ni][0] + bias, acc[mi][ni][1] + bias,
                                       acc[mi][ni][2] + bias, acc[mi][ni][3] + bias);
                *(float4*)(dst + pxb) = v;
            }
        }
    }
}

// ---------------- decode (+ fused byte-3 histogram for topk) ----------------
__global__ __launch_bounds__(256) void decode_kernel(
    const float* __restrict__ cls_s, const float* __restrict__ bbox_p,
    const float* __restrict__ anchors,
    unsigned int* __restrict__ keys, float* __restrict__ boxes,
    unsigned int* __restrict__ ghist) {
    __shared__ unsigned int lh[256];
    int t = threadIdx.x;
    lh[t] = 0u;
    __syncthreads();
    int i = blockIdx.x * 256 + t;
    if (i < NANCH) {
        int pix = i / AA;
        int a = i - pix * AA;
        float s0 = cls_s[(size_t)a * NPIX + pix];
        float s1 = cls_s[(size_t)(AA + a) * NPIX + pix];
        float d = s1 - s0;
        unsigned int u = __float_as_uint(d);
        unsigned int key = (u & 0x80000000u) ? ~u : (u | 0x80000000u);
        keys[i] = key;
        atomicAdd(&lh[key >> 24], 1u);

        float dx = bbox_p[(size_t)(4 * a + 0) * NPIX + pix];
        float dy = bbox_p[(size_t)(4 * a + 1) * NPIX + pix];
        float dw = bbox_p[(size_t)(4 * a + 2) * NPIX + pix];
        float dh = bbox_p[(size_t)(4 * a + 3) * NPIX + pix];
        float ax1 = anchors[(size_t)i * 4 + 0];
        float ay1 = anchors[(size_t)i * 4 + 1];
        float ax2 = anchors[(size_t)i * 4 + 2];
        float ay2 = anchors[(size_t)i * 4 + 3];
        float aw = ax2 - ax1 + 1.f;
        float ah = ay2 - ay1 + 1.f;
        float acx = ax1 + 0.5f * aw;
        float acy = ay1 + 0.5f * ah;
        float pcx = dx * aw + acx;
        float pcy = dy * ah + acy;
        float pw = __expf(dw) * aw;
        float ph = __expf(dh) * ah;
        const float XMAX = 16.f * WW - 1.f;
        const float YMAX = 16.f * HH - 1.f;
        boxes[(size_t)i * 4 + 0] = fminf(fmaxf(pcx - 0.5f * pw, 0.f), XMAX);
        boxes[(size_t)i * 4 + 1] = fminf(fmaxf(pcy - 0.5f * ph, 0.f), YMAX);
        boxes[(size_t)i * 4 + 2] = fminf(fmaxf(pcx + 0.5f * pw, 0.f), XMAX);
        boxes[(size_t)i * 4 + 3] = fminf(fmaxf(pcy + 0.5f * ph, 0.f), YMAX);
    }
    __syncthreads();
    if (lh[t]) atomicAdd(&ghist[t], lh[t]);
}

// ---------------- exact top-k (byte-3 histogram precomputed by decode) ----------------
__global__ __launch_bounds__(1024) void topk_kernel(const unsigned int* __restrict__ keys,
                                                    const unsigned int* __restrict__ ghist,
                                                    int* __restrict__ top_idx) {
    const int N = NANCH, K = TOPN;
    __shared__ unsigned int s_prefix;
    __shared__ int s_k;
    __shared__ unsigned int hist[256];
    __shared__ int s_ngt, s_neq;
    __shared__ unsigned long long s_sel[512];
    __shared__ int s_eq[1024];
    int tid = threadIdx.x;
    if (tid == 0) { s_prefix = 0u; s_k = K; }
    __syncthreads();

    for (int d = 3; d >= 0; --d) {
        if (tid < 256) hist[tid] = (d == 3) ? ghist[tid] : 0u;
        __syncthreads();
        unsigned int pfx = s_prefix;
        int shift = d * 8;
        if (d < 3) {
            unsigned int maskHigh = ~((1u << ((d + 1) * 8)) - 1u);
            for (int i = tid; i < N; i += 1024) {
                unsigned int k = keys[i];
                if ((k & maskHigh) == (pfx & maskHigh))
                    atomicAdd(&hist[(k >> shift) & 255u], 1u);
            }
        }
        __syncthreads();
        if (tid == 0) {
            int kk = s_k;
            int cum = 0;
            unsigned int sel = 0;
            for (int v = 255; v >= 0; v--) {
                int hcnt = (int)hist[v];
                if (cum + hcnt >= kk) { sel = (unsigned int)v; s_k = kk - cum; break; }
                cum += hcnt;
            }
            s_prefix = pfx | (sel << shift);
        }
        __syncthreads();
    }
    unsigned int T = s_prefix;
    int krem = s_k;
    if (tid == 0) { s_ngt = 0; s_neq = 0; }
    __syncthreads();
    for (int i = tid; i < N; i += 1024) {
        unsigned int k = keys[i];
        if (k > T) {
            int p = atomicAdd(&s_ngt, 1);
            if (p < 512)
                s_sel[p] = ((unsigned long long)k << 32) | (unsigned int)(~(unsigned int)i);
        } else if (k == T) {
            int p = atomicAdd(&s_neq, 1);
            if (p < 1024) s_eq[p] = i;
        }
    }
    __syncthreads();
    int ngt = min(s_ngt, 512);
    int neq = min(s_neq, 1024);
    for (int e = tid; e < neq; e += 1024) {
        int idx = s_eq[e];
        int rank = 0;
        for (int j = 0; j < neq; j++)
            if (s_eq[j] < idx) rank++;
        if (rank < krem && ngt + rank < 512)
            s_sel[ngt + rank] = ((unsigned long long)T << 32) | (unsigned int)(~(unsigned int)idx);
    }
    __syncthreads();
    for (int p = K + tid; p < 512; p += 1024) s_sel[p] = 0ULL;
    __syncthreads();
    for (unsigned int k2 = 2; k2 <= 512; k2 <<= 1) {
        for (unsigned int j = k2 >> 1; j > 0; j >>= 1) {
            if (tid < 512) {
                int i = tid;
                int ixj = i ^ (int)j;
                if (ixj > i) {
                    unsigned long long a = s_sel[i], cc = s_sel[ixj];
                    bool up = ((i & k2) == 0);
                    if (up ? (a > cc) : (a < cc)) { s_sel[i] = cc; s_sel[ixj] = a; }
                }
            }
            __syncthreads();
        }
    }
    if (tid < K)
        top_idx[tid] = (int)(~(unsigned int)(s_sel[511 - tid] & 0xFFFFFFFFull));
}

// ---------------- roi align from Fpix -> pooled (n,q,c) bf16 ----------------
__global__ __launch_bounds__(256) void roialign_kernel(
    const unsigned short* __restrict__ Fpix, const float* __restrict__ boxes,
    const int* __restrict__ top_idx, unsigned short* __restrict__ pooled) {
    int n = blockIdx.x;
    int q = blockIdx.y;
    int ph = q / 7, pw = q - ph * 7;
    int bi = top_idx[n];
    float x1 = boxes[(size_t)bi * 4 + 0] * (1.f / 16.f);
    float y1 = boxes[(size_t)bi * 4 + 1] * (1.f / 16.f);
    float x2 = boxes[(size_t)bi * 4 + 2] * (1.f / 16.f);
    float y2 = boxes[(size_t)bi * 4 + 3] * (1.f / 16.f);
    float gx = (pw + 0.5f) / 7.f;
    float gy = (ph + 0.5f) / 7.f;
    float xs = fminf(fmaxf(x1 + (x2 - x1) * gx, 0.f), (float)(WW - 1));
    float ys = fminf(fmaxf(y1 + (y2 - y1) * gy, 0.f), (float)(HH - 1));
    float x0f = floorf(xs), y0f = floorf(ys);
    int x0 = (int)x0f, y0 = (int)y0f;
    int x1i = min(x0 + 1, WW - 1);
    int y1i = min(y0 + 1, HH - 1);
    float wx = xs - x0f, wy = ys - y0f;
    float w00 = (1.f - wy) * (1.f - wx), w01 = (1.f - wy) * wx;
    float w10 = wy * (1.f - wx), w11 = wy * wx;
    const unsigned short* r00 = Fpix + (size_t)((y0 + 1) * PW + x0 + 1) * 1024;
    const unsigned short* r01 = Fpix + (size_t)((y0 + 1) * PW + x1i + 1) * 1024;
    const unsigned short* r10 = Fpix + (size_t)((y1i + 1) * PW + x0 + 1) * 1024;
    const unsigned short* r11 = Fpix + (size_t)((y1i + 1) * PW + x1i + 1) * 1024;
    unsigned short* dst = pooled + (size_t)n * KFC + (size_t)q * CIN;
    int c = threadIdx.x * 4;
    ushort4 a = *(const ushort4*)(r00 + c);
    ushort4 b = *(const ushort4*)(r01 + c);
    ushort4 cc = *(const ushort4*)(r10 + c);
    ushort4 d = *(const ushort4*)(r11 + c);
    ushort4 o;
    o.x = f2bf(w00 * bf2f(a.x) + w01 * bf2f(b.x) + w10 * bf2f(cc.x) + w11 * bf2f(d.x));
    o.y = f2bf(w00 * bf2f(a.y) + w01 * bf2f(b.y) + w10 * bf2f(cc.y) + w11 * bf2f(d.y));
    o.z = f2bf(w00 * bf2f(a.z) + w01 * bf2f(b.z) + w10 * bf2f(cc.z) + w11 * bf2f(d.z));
    o.w = f2bf(w00 * bf2f(a.w) + w01 * bf2f(b.w) + w10 * bf2f(cc.w) + w11 * bf2f(d.w));
    *(ushort4*)(dst + c) = o;
}

// ---------------- FC GEMM via MFMA: fc7p[kz] = pooled @ fc_w (kz k-slice) ----------
// grid 256: kz = b&7 (XCD-affine), j-tile = b>>3 (64 cols). Block: 320 px x 64 col.
// v2: plain stores to per-kz slab (no atomics); W conversion via v_cvt_pk_bf16_f32.
__global__ __launch_bounds__(256) void fc_mfma_kernel(
    const unsigned short* __restrict__ pooled, const float* __restrict__ fc_w,
    float* __restrict__ fc7p) {
    __shared__ __align__(16) unsigned short As[320 * 42];
    __shared__ __align__(16) unsigned short Ws[64 * 42];
    const int tid = threadIdx.x;
    const int b = blockIdx.x;
    const int kz = b & 7;
    const int j0 = (b >> 3) * 64;
    const int lane = tid & 63, wv = tid >> 6;
    const int lane16 = lane & 15, quad = lane >> 4;
    const int m0 = wv * 80;
    const int kbase = kz * 6272;
    const int g = tid >> 4;              // W staging: krow pair 2g, 2g+1
    const int col4 = (tid & 15) * 4;

    f32x4 acc[5][4];
#pragma unroll
    for (int mi = 0; mi < 5; mi++)
#pragma unroll
        for (int ni = 0; ni < 4; ni++) acc[mi][ni] = (f32x4){0.f, 0.f, 0.f, 0.f};

    short8 rA[5];
    float4 rW0[2], rW1[2];

#define LOAD_A(cIdx)                                                              \
    {                                                                             \
        int k0_ = kbase + (cIdx) * 32;                                            \
        _Pragma("unroll")                                                         \
        for (int i = 0; i < 5; i++) {                                             \
            int lid = tid + 256 * i;                                              \
            int row = lid >> 2, seg = lid & 3;                                    \
            rA[i] = (row < TOPN)                                                  \
                  ? *(const short8*)(pooled + (size_t)row * KFC + k0_ + seg * 8)  \
                  : (short8){0, 0, 0, 0, 0, 0, 0, 0};                             \
        }                                                                         \
    }
#define LOAD_W(cIdx, dst)                                                         \
    {                                                                             \
        int k0_ = kbase + (cIdx) * 32;                                            \
        int q_ = k0_ >> 10, c0_ = k0_ & 1023;                                     \
        _Pragma("unroll")                                                         \
        for (int u = 0; u < 2; u++)                                               \
            dst[u] = *(const float4*)(fc_w +                                      \
                ((size_t)(c0_ + 2 * g + u) * 49 + q_) * FCDIM + j0 + col4);       \
    }

    LOAD_A(0);
    LOAD_W(0, rW0);
    LOAD_W(1, rW1);

    for (int c = 0; c < 196; ++c) {
        __syncthreads();
#pragma unroll
        for (int i = 0; i < 5; i++) {
            int lid = tid + 256 * i;
            int row = lid >> 2, seg = lid & 3;
            *(short8*)&As[row * 42 + seg * 8] = rA[i];
        }
        {
            float* p0 = (float*)&rW0[0];
            float* p1 = (float*)&rW0[1];
#pragma unroll
            for (int v = 0; v < 4; v++)
                *(unsigned int*)&Ws[(col4 + v) * 42 + 2 * g] = cvt_pk_bf16(p0[v], p1[v]);
        }
        if (c + 1 < 196) LOAD_A(c + 1);
        rW0[0] = rW1[0]; rW0[1] = rW1[1];
        if (c + 2 < 196) LOAD_W(c + 2, rW1);
        __syncthreads();
        short8 af[5], bfr[4];
#pragma unroll
        for (int mi = 0; mi < 5; mi++)
            af[mi] = *(const short8*)&As[(m0 + mi * 16 + lane16) * 42 + quad * 8];
#pragma unroll
        for (int ni = 0; ni < 4; ni++)
            bfr[ni] = *(const short8*)&Ws[(ni * 16 + lane16) * 42 + quad * 8];
#pragma unroll
        for (int mi = 0; mi < 5; mi++)
#pragma unroll
            for (int ni = 0; ni < 4; ni++)
                acc[mi][ni] = __builtin_amdgcn_mfma_f32_16x16x32_bf16(af[mi], bfr[ni],
                                                                     acc[mi][ni], 0, 0, 0);
    }
#undef LOAD_A
#undef LOAD_W
    float* dst = fc7p + (size_t)kz * (TOPN * FCDIM);
#pragma unroll
    for (int mi = 0; mi < 5; mi++) {
#pragma unroll
        for (int r = 0; r < 4; r++) {
            int m = m0 + mi * 16 + quad * 4 + r;
            if (m < TOPN) {
#pragma unroll
                for (int ni = 0; ni < 4; ni++)
                    dst[(size_t)m * FCDIM + j0 + ni * 16 + lane16] = acc[mi][ni][r];
            }
        }
    }
}

// ---------------- fc7 = sum of 8 kz slabs + bias + relu ----------------
__global__ void bias_relu_kernel(const float* __restrict__ fc7p,
                                 const float* __restrict__ fc_b,
                                 float* __restrict__ fc7) {
    int i = blockIdx.x * 256 + threadIdx.x;
    if (i < TOPN * FCDIM) {
        float s = 0.f;
#pragma unroll
        for (int z = 0; z < 8; z++) s += fc7p[(size_t)z * (TOPN * FCDIM) + i];
        fc7[i] = fmaxf(s + fc_b[i & (FCDIM - 1)], 0.f);
    }
}

// ---------------- head GEMMs ----------------
__global__ __launch_bounds__(128) void head_gemm_kernel(
    const float* __restrict__ fc7,
    const float* __restrict__ cw, const float* __restrict__ cb,
    const float* __restrict__ bw, const float* __restrict__ bb,
    float* __restrict__ cls_score, float* __restrict__ bbox_pred) {
    int n = blockIdx.x;
    __shared__ float row[FCDIM];
    for (int k = threadIdx.x; k < FCDIM; k += 128) row[k] = fc7[(size_t)n * FCDIM + k];
    __syncthreads();
    int t = threadIdx.x;
    if (t < 21) {
        float acc = 0.f;
        for (int k = 0; k < FCDIM; k += 4) {
#pragma unroll
            for (int u = 0; u < 4; u++) acc += row[k + u] * cw[(size_t)(k + u) * 21 + t];
        }
        cls_score[n * 21 + t] = acc + cb[t];
    } else if (t < 105) {
        int oc = t - 21;
        float acc = 0.f;
        for (int k = 0; k < FCDIM; k += 4) {
#pragma unroll
            for (int u = 0; u < 4; u++) acc += row[k + u] * bw[(size_t)(k + u) * 84 + oc];
        }
        bbox_pred[n * 84 + oc] = acc + bb[oc];
    }
}

// ---------------- losses ----------------
__device__ __forceinline__ void block_atomic_acc(float v, float* dst) {
    for (int o = 32; o > 0; o >>= 1) v += __shfl_down(v, o);
    if ((threadIdx.x & 63) == 0) atomicAdd(dst, v);
}

__global__ void loss_rpn_ce_kernel(const float* __restrict__ cls_s,
                                   const int* __restrict__ labels, float* __restrict__ acc) {
    int i = blockIdx.x * 256 + threadIdx.x;
    float ce = 0.f, cnt = 0.f;
    if (i < NANCH) {
        int lab = labels[i];
        if (lab != -1) {
            int a = i / NPIX, pix = i - a * NPIX;
            float s0 = cls_s[(size_t)a * NPIX + pix];
            float s1 = cls_s[(size_t)(AA + a) * NPIX + pix];
            float m = fmaxf(s0, s1);
            float lse = m + logf(expf(s0 - m) + expf(s1 - m));
            ce = lse - (lab ? s1 : s0);
            cnt = 1.f;
        }
    }
    block_atomic_acc(ce, &acc[0]);
    block_atomic_acc(cnt, &acc[1]);
}

__global__ void loss_rpn_bbox_kernel(const float* __restrict__ bbox_p,
                                     const float* __restrict__ tgt,
                                     const float* __restrict__ biw,
                                     const float* __restrict__ bow, float* __restrict__ acc) {
    int e = blockIdx.x * 256 + threadIdx.x;
    float contrib = 0.f;
    if (e < NPIX * 36) {
        int pix = e / 36, c = e - pix * 36;
        float pred = bbox_p[(size_t)c * NPIX + pix];
        float d = biw[e] * (pred - tgt[e]);
        float ad = fabsf(d);
        float l = (ad < (1.f / 9.f)) ? d * d * 4.5f : ad - (1.f / 18.f);
        contrib = bow[e] * l;
    }
    block_atomic_acc(contrib, &acc[2]);
}

__global__ void loss_cls_kernel(const float* __restrict__ cls_score,
                                const int* __restrict__ labels, float* __restrict__ acc) {
    int n = blockIdx.x * 256 + threadIdx.x;
    float ce = 0.f;
    if (n < TOPN) {
        const float* lg = cls_score + n * 21;
        float m = lg[0];
        for (int j = 1; j < 21; j++) m = fmaxf(m, lg[j]);
        float s = 0.f;
        for (int j = 0; j < 21; j++) s += expf(lg[j] - m);
        ce = m + logf(s) - lg[labels[n]];
    }
    block_atomic_acc(ce, &acc[3]);
}

__global__ void loss_roi_bbox_kernel(const float* __restrict__ bbox_pred,
                                     const float* __restrict__ tgt,
                                     const float* __restrict__ biw,
                                     const float* __restrict__ bow, float* __restrict__ acc) {
    int e = blockIdx.x * 256 + threadIdx.x;
    float contrib = 0.f;
    if (e < TOPN * 84) {
        float d = biw[e] * (bbox_pred[e] - tgt[e]);
        float ad = fabsf(d);
        float l = (ad < 1.f) ? 0.5f * d * d : ad - 0.5f;
        contrib = bow[e] * l;
    }
    block_atomic_acc(contrib, &acc[4]);
}

__global__ void finalize_kernel(const float* __restrict__ acc, float* __restrict__ out) {
    out[0] = acc[0] / fmaxf(acc[1], 1.f) + acc[2]
           + acc[3] * (1.f / TOPN) + acc[4] * (1.f / TOPN);
}

// ---------------- launch ----------------
extern "C" void kernel_launch(void* const* d_in, const int* in_sizes, int n_in,
                              void* d_out, int out_size, void* d_ws, size_t ws_size,
                              hipStream_t stream) {
    const float* net_conv   = (const float*)d_in[0];
    const float* rpn_w      = (const float*)d_in[1];
    const float* rpn_b      = (const float*)d_in[2];
    const float* rpn_cls_w  = (const float*)d_in[3];
    const float* rpn_cls_b  = (const float*)d_in[4];
    const float* rpn_bbox_w = (const float*)d_in[5];
    const float* rpn_bbox_b = (const float*)d_in[6];
    const float* fc_w       = (const float*)d_in[7];
    const float* fc_b       = (const float*)d_in[8];
    const float* cls_w      = (const float*)d_in[9];
    const float* cls_b      = (const float*)d_in[10];
    const float* bbox_w     = (const float*)d_in[11];
    const float* bbox_b     = (const float*)d_in[12];
    const float* anchors    = (const float*)d_in[13];
    const float* rpn_bt     = (const float*)d_in[14];
    const float* rpn_biw    = (const float*)d_in[15];
    const float* rpn_bow    = (const float*)d_in[16];
    const float* roi_bt     = (const float*)d_in[17];
    const float* roi_biw    = (const float*)d_in[18];
    const float* roi_bow    = (const float*)d_in[19];
    const int* rpn_labels   = (const int*)d_in[20];
    const int* roi_labels   = (const int*)d_in[21];

    char* base = (char*)d_ws;
    unsigned short* Fpix = (unsigned short*)base;
    const size_t FPIX_BYTES = (size_t)FPIX_ROWS * 1024 * 2;  // 20,463,616
    unsigned short* Wb = (unsigned short*)(base + FPIX_BYTES);
    unsigned short* rpn = (unsigned short*)(base + 29900800);  // [9120][512] bf16
    unsigned short* pooled = (unsigned short*)(base + FPIX_BYTES);
    size_t off = 50569216;
    float* cls_s = (float*)(base + off);      off += 656640;
    float* bbox_p = (float*)(base + off);     off += 1313280;
    unsigned int* keys = (unsigned int*)(base + off); off += 328448;
    float* boxes = (float*)(base + off);      off += 1313280;
    int* top_idx = (int*)(base + off);        off += 1280;
    float* cls_score = (float*)(base + off);  off += 25600;
    float* bbox_pred = (float*)(base + off);  off += 100864;
    float* fc7 = (float*)(base + off);        off += 2457600;
    float* accum = (float*)(base + off);      off += 256;
    unsigned int* hist = (unsigned int*)(base + off); off += 1024;
    float* fc7p = (float*)(base + off);       off += 19660800;  // 8 x 300 x 2048 f32
    float* out = (float*)d_out;

    zero4_kernel<<<(int)((FPIX_BYTES / 16 + 255) / 256), 256, 0, stream>>>((float4*)Fpix,
                                                                           (int)(FPIX_BYTES / 16));
    fpix_fill_kernel<<<dim3(143, 16), 256, 0, stream>>>(net_conv, Fpix);
    wb_fill_kernel<<<2048, 256, 0, stream>>>(rpn_w, Wb);
    zero_kernel<<<2, 256, 0, stream>>>(accum, 64 + 256);   // accum + hist

    conv_mfma_kernel<<<640, 256, 0, stream>>>(Fpix, Wb, rpn_b, rpn);
    heads_mfma_kernel<<<72, 256, 0, stream>>>(rpn, rpn_cls_w, rpn_cls_b,
                                              rpn_bbox_w, rpn_bbox_b, cls_s, bbox_p);
    decode_kernel<<<(NANCH + 255) / 256, 256, 0, stream>>>(cls_s, bbox_p, anchors, keys,
                                                           boxes, hist);
    topk_kernel<<<1, 1024, 0, stream>>>(keys, hist, top_idx);
    roialign_kernel<<<dim3(300, 49), 256, 0, stream>>>(Fpix, boxes, top_idx, pooled);
    fc_mfma_kernel<<<256, 256, 0, stream>>>(pooled, fc_w, fc7p);
    bias_relu_kernel<<<(TOPN * FCDIM + 255) / 256, 256, 0, stream>>>(fc7p, fc_b, fc7);
    head_gemm_kernel<<<300, 128, 0, stream>>>(fc7, cls_w, cls_b, bbox_w, bbox_b,
                                              cls_score, bbox_pred);
    loss_rpn_ce_kernel<<<(NANCH + 255) / 256, 256, 0, stream>>>(cls_s, rpn_labels, accum);
    loss_rpn_bbox_kernel<<<(NPIX * 36 + 255) / 256, 256, 0, stream>>>(bbox_p, rpn_bt,
                                                                      rpn_biw, rpn_bow, accum);
    loss_cls_kernel<<<2, 256, 0, stream>>>(cls_score, roi_labels, accum);
    loss_roi_bbox_kernel<<<(TOPN * 84 + 255) / 256, 256, 0, stream>>>(bbox_pred, roi_bt,
                                                                      roi_biw, roi_bow, accum);
    finalize_kernel<<<1, 1, 0, stream>>>(accum, out);
}

// Round 4
// 1209.208 us; speedup vs baseline: 1.2265x; 1.0085x over previous
//
#include <hip/hip_runtime.h>
#include <cstddef>

#define HH 76
#define WW 120
#define NPIX (HH*WW)          // 9120
#define AA 9
#define NANCH (NPIX*AA)       // 82080
#define TOPN 300
#define CIN 1024
#define CMID 512
#define FCDIM 2048
#define KFC (CIN*49)          // 50176
#define PW 128
#define PROWS (78*128)        // 9984 padded pixel rows
#define FPIX_ROWS (PROWS + 8)
#define NKZ 16                // fc K-slices

typedef __attribute__((ext_vector_type(8))) short short8;
typedef __attribute__((ext_vector_type(4))) float f32x4;

__device__ __forceinline__ float bf2f(unsigned short h) {
    return __uint_as_float(((unsigned int)h) << 16);
}
__device__ __forceinline__ unsigned short f2bf(float f) {
    unsigned int u = __float_as_uint(f);
    unsigned int r = (u + 0x7FFFu + ((u >> 16) & 1u)) >> 16;
    return (unsigned short)r;
}
// packed f32x2 -> bf16x2 (RNE), single instruction
__device__ __forceinline__ unsigned int cvt_pk_bf16(float lo, float hi) {
    unsigned int r;
    asm("v_cvt_pk_bf16_f32 %0, %1, %2" : "=v"(r) : "v"(lo), "v"(hi));
    return r;
}

// async global->LDS, 16B per lane. LDS dest = wave-uniform base + lane*16.
__device__ __forceinline__ void gld16(const unsigned short* g, unsigned short* l) {
    __builtin_amdgcn_global_load_lds(
        (const __attribute__((address_space(1))) unsigned int*)(g),
        (__attribute__((address_space(3))) unsigned int*)(l),
        16, 0, 0);
}

// ---------------- zero init ----------------
__global__ void zero_kernel(float* __restrict__ p, int n) {
    int i = blockIdx.x * 256 + threadIdx.x;
    if (i < n) p[i] = 0.f;
}
__global__ void zero4_kernel(float4* __restrict__ p, int n4) {
    int i = blockIdx.x * 256 + threadIdx.x;
    if (i < n4) p[i] = make_float4(0.f, 0.f, 0.f, 0.f);
}

// ---------------- Fpix fill: [ic][px] fp32 -> [padded px][ic] bf16 ----------------
__global__ __launch_bounds__(256) void fpix_fill_kernel(const float* __restrict__ F,
                                                        unsigned short* __restrict__ Fpix) {
    __shared__ float s[64][65];
    int px0 = blockIdx.x * 64, ic0 = blockIdx.y * 64;
    int t = threadIdx.x;
#pragma unroll 4
    for (int i = 0; i < 16; i++) {
        int ic = (t >> 6) + i * 4;
        int px = px0 + (t & 63);
        float v = (px < NPIX) ? F[(size_t)(ic0 + ic) * NPIX + px] : 0.f;
        s[t & 63][ic] = v;
    }
    __syncthreads();
    int pxl = t >> 2;
    int px = px0 + pxl;
    if (px < NPIX) {
        int h = px / 120, w = px - h * 120;
        size_t prow = (size_t)(h + 1) * PW + (w + 1);
        unsigned short* dst = Fpix + prow * 1024 + ic0 + (t & 3) * 16;
#pragma unroll
        for (int u = 0; u < 16; u++) dst[u] = f2bf(s[pxl][(t & 3) * 16 + u]);
    }
}

// ---------------- Wb fill: [ocic][9] fp32 -> [tap][ocic] bf16 (LDS transpose) ----------------
__global__ __launch_bounds__(256) void wb_fill_kernel(const float* __restrict__ Wsrc,
                                                      unsigned short* __restrict__ Wb) {
    __shared__ float s[2304];
    int r0 = blockIdx.x * 256;
    int t = threadIdx.x;
    const float4* src4 = (const float4*)(Wsrc + (size_t)r0 * 9);
#pragma unroll
    for (int i = 0; i < 3; i++) {
        int idx = t + 256 * i;
        if (idx < 576) *(float4*)&s[idx * 4] = src4[idx];
    }
    __syncthreads();
#pragma unroll
    for (int tap = 0; tap < 9; tap++)
        Wb[(size_t)tap * 524288 + r0 + t] = f2bf(s[t * 9 + tap]);
}

// ---------------- conv 3x3 via MFMA implicit GEMM -> rpn pixel-major [px][512] ----------------
// v5: 64x64 tile, LDS 32KB -> ~5 blocks/CU co-resident (TLP hides the 2-phase
// barrier/stage stall, m114/m233). Grid 1280 = 8 XCD x (10 h x 8 oct x 2 half);
// each XCD keeps its contiguous h-chunk (T1). T2 XOR swizzle + counted vmcnt kept.
__global__ __launch_bounds__(256) void conv_mfma_kernel(
    const unsigned short* __restrict__ Fpix,
    const unsigned short* __restrict__ Wb,
    const float* __restrict__ Bs,
    unsigned short* __restrict__ out) {       // [9120][512] bf16
    __shared__ __align__(16) unsigned short As[2][64 * 64];  // [buf][px][64 ic-shorts]
    __shared__ __align__(16) unsigned short Ws[2][64 * 64];  // [buf][oc][64 ic-shorts]
    const int tid = threadIdx.x;
    const int flat = blockIdx.x;
    const int xcd = flat & 7;
    const int r = flat >> 3;            // 0..159
    const int half = r & 1;
    const int oct = (r >> 1) & 7;
    const int h = xcd * 10 + (r >> 4);  // contiguous h-chunk per XCD
    if (h >= HH) return;
    const int px0 = half * 64;
    const int lane = tid & 63, wv = tid >> 6;
    const int lane16 = lane & 15, quad = lane >> 4;
    const int wave_px = (wv & 1) * 32, wave_oc = (wv >> 1) * 32;
    const int wvb = wv * 64;            // wave slot base for staging

    f32x4 acc[2][2];
#pragma unroll
    for (int mi = 0; mi < 2; mi++)
#pragma unroll
        for (int ni = 0; ni < 2; ni++) acc[mi][ni] = (f32x4){0.f, 0.f, 0.f, 0.f};

    // chunk cc in [0,144): tap = cc>>4, ic0 = (cc&15)*64 shorts.
    // A: 2 rounds of 256 lanes; slot = u*256+tid -> px = slot>>3 (0..63), sp = slot&7;
    //    global seg = sp ^ (px&7) (inverse swizzle). B: same with oc.
#define CONV_STAGE(cc, Ab, Wsb)                                                           \
    do {                                                                                  \
        int tap_ = (cc) >> 4;                                                             \
        int ic0_ = ((cc) & 15) << 6;                                                      \
        int dh_ = (tap_ * 11) >> 5;                                                       \
        int dw_ = tap_ - dh_ * 3;                                                         \
        _Pragma("unroll")                                                                 \
        for (int u_ = 0; u_ < 2; u_++) {                                                  \
            int slot_ = u_ * 256 + tid;                                                   \
            int px_ = slot_ >> 3, sp_ = slot_ & 7;                                        \
            const unsigned short* src_ =                                                  \
                Fpix + (size_t)((h + dh_) * PW + px0 + px_ + dw_) * 1024 + ic0_           \
                     + ((sp_ ^ (px_ & 7)) << 3);                                          \
            gld16(src_, (Ab) + (size_t)(u_ * 256 + wvb) * 8);                             \
        }                                                                                 \
        _Pragma("unroll")                                                                 \
        for (int u_ = 0; u_ < 2; u_++) {                                                  \
            int slot_ = u_ * 256 + tid;                                                   \
            int oc_ = slot_ >> 3, sp_ = slot_ & 7;                                        \
            const unsigned short* src_ =                                                  \
                Wb + (size_t)(tap_ * 512 + oct * 64 + oc_) * 1024 + ic0_                  \
                   + ((sp_ ^ (oc_ & 7)) << 3);                                            \
            gld16(src_, (Wsb) + (size_t)(u_ * 256 + wvb) * 8);                            \
        }                                                                                 \
    } while (0)

    CONV_STAGE(0, &As[0][0], &Ws[0][0]);

    int cur = 0;
    for (int c = 0; c < 144; ++c) {
        if (c + 1 < 144) {
            CONV_STAGE(c + 1, &As[cur ^ 1][0], &Ws[cur ^ 1][0]);
            asm volatile("s_waitcnt vmcnt(4)" ::: "memory");  // stage(c) landed; 4 in flight
        } else {
            asm volatile("s_waitcnt vmcnt(0)" ::: "memory");  // final tile
        }
        __builtin_amdgcn_s_barrier();        // all waves' stage(c) visible
        asm volatile("" ::: "memory");       // pin ds_reads below the barrier
        const unsigned short* Ac = &As[cur][0];
        const unsigned short* Wc = &Ws[cur][0];
#pragma unroll
        for (int kk = 0; kk < 2; kk++) {
            short8 af[2], bfr[2];
#pragma unroll
            for (int mi = 0; mi < 2; mi++) {
                int px = wave_px + mi * 16 + lane16;
                af[mi] = *(const short8*)&Ac[px * 64 + (((kk * 4 + quad) ^ (px & 7)) << 3)];
            }
#pragma unroll
            for (int ni = 0; ni < 2; ni++) {
                int oc = wave_oc + ni * 16 + lane16;
                bfr[ni] = *(const short8*)&Wc[oc * 64 + (((kk * 4 + quad) ^ (oc & 7)) << 3)];
            }
#pragma unroll
            for (int mi = 0; mi < 2; mi++)
#pragma unroll
                for (int ni = 0; ni < 2; ni++)
                    acc[mi][ni] = __builtin_amdgcn_mfma_f32_16x16x32_bf16(
                        af[mi], bfr[ni], acc[mi][ni], 0, 0, 0);
        }
        asm volatile("s_waitcnt lgkmcnt(0)" ::: "memory");  // all LDS reads retired
        __builtin_amdgcn_s_barrier();        // safe to overwrite buf[cur] next iter
        cur ^= 1;
    }
#undef CONV_STAGE

    // epilogue -> pixel-major rpn
#pragma unroll
    for (int ni = 0; ni < 2; ni++) {
        int oc = oct * 64 + wave_oc + ni * 16 + lane16;
        float bias = Bs[oc];
#pragma unroll
        for (int mi = 0; mi < 2; mi++) {
#pragma unroll
            for (int r2 = 0; r2 < 4; r2++) {
                int px = px0 + wave_px + mi * 16 + quad * 4 + r2;
                if (px < 120)
                    out[(size_t)(h * 120 + px) * 512 + oc] =
                        f2bf(fmaxf(acc[mi][ni][r2] + bias, 0.f));
            }
        }
    }
}

// ---------------- heads via MFMA: [9120 px][512] @ [54][512]^T -> cls_s, bbox_p ----------------
__global__ __launch_bounds__(256) void heads_mfma_kernel(
    const unsigned short* __restrict__ rpn,   // [9120][512] bf16
    const float* __restrict__ cw, const float* __restrict__ cb,
    const float* __restrict__ bw, const float* __restrict__ bb,
    float* __restrict__ cls_s, float* __restrict__ bbox_p) {
    __shared__ __align__(16) unsigned short As[128 * 42];
    __shared__ __align__(16) unsigned short Ws[64 * 42];
    const int tid = threadIdx.x;
    const int px0 = blockIdx.x * 128;
    const int lane = tid & 63, wv = tid >> 6;
    const int lane16 = lane & 15, quad = lane >> 4;
    const int wave_px = (wv & 1) * 64, wave_oc = (wv >> 1) * 32;

    f32x4 acc[4][2];
#pragma unroll
    for (int mi = 0; mi < 4; mi++)
#pragma unroll
        for (int ni = 0; ni < 2; ni++) acc[mi][ni] = (f32x4){0.f, 0.f, 0.f, 0.f};

    const int wn = tid >> 2, wseg = tid & 3;   // W staging: n, 8-float segment
    const float* wsrc = (wn < 18) ? (cw + (size_t)wn * 512)
                      : (wn < 54) ? (bw + (size_t)(wn - 18) * 512) : nullptr;

    short8 rA[2];
    float4 rw0, rw1;
    {
        int k0 = 0;
#pragma unroll
        for (int u = 0; u < 2; u++) {
            int lid = tid + 256 * u;
            int row = lid >> 2, seg = lid & 3;
            int px = px0 + row;
            rA[u] = (px < NPIX) ? *(const short8*)(rpn + (size_t)px * 512 + k0 + seg * 8)
                                : (short8){0, 0, 0, 0, 0, 0, 0, 0};
        }
        if (wsrc) {
            rw0 = *(const float4*)(wsrc + k0 + wseg * 8);
            rw1 = *(const float4*)(wsrc + k0 + wseg * 8 + 4);
        } else { rw0 = make_float4(0, 0, 0, 0); rw1 = rw0; }
    }
    for (int c = 0; c < 16; ++c) {
        __syncthreads();
#pragma unroll
        for (int u = 0; u < 2; u++) {
            int lid = tid + 256 * u;
            int row = lid >> 2, seg = lid & 3;
            *(short8*)&As[row * 42 + seg * 8] = rA[u];
        }
        {
            unsigned int* wp = (unsigned int*)&Ws[wn * 42 + wseg * 8];
            wp[0] = cvt_pk_bf16(rw0.x, rw0.y);
            wp[1] = cvt_pk_bf16(rw0.z, rw0.w);
            wp[2] = cvt_pk_bf16(rw1.x, rw1.y);
            wp[3] = cvt_pk_bf16(rw1.z, rw1.w);
        }
        if (c + 1 < 16) {
            int k0 = (c + 1) * 32;
#pragma unroll
            for (int u = 0; u < 2; u++) {
                int lid = tid + 256 * u;
                int row = lid >> 2, seg = lid & 3;
                int px = px0 + row;
                rA[u] = (px < NPIX) ? *(const short8*)(rpn + (size_t)px * 512 + k0 + seg * 8)
                                    : (short8){0, 0, 0, 0, 0, 0, 0, 0};
            }
            if (wsrc) {
                rw0 = *(const float4*)(wsrc + k0 + wseg * 8);
                rw1 = *(const float4*)(wsrc + k0 + wseg * 8 + 4);
            }
        }
        __syncthreads();
        short8 af[4], bfr[2];
#pragma unroll
        for (int mi = 0; mi < 4; mi++)
            af[mi] = *(const short8*)&As[(wave_px + mi * 16 + lane16) * 42 + quad * 8];
#pragma unroll
        for (int ni = 0; ni < 2; ni++)
            bfr[ni] = *(const short8*)&Ws[(wave_oc + ni * 16 + lane16) * 42 + quad * 8];
#pragma unroll
        for (int mi = 0; mi < 4; mi++)
#pragma unroll
            for (int ni = 0; ni < 2; ni++)
                acc[mi][ni] = __builtin_amdgcn_mfma_f32_16x16x32_bf16(af[mi], bfr[ni],
                                                                     acc[mi][ni], 0, 0, 0);
    }
#pragma unroll
    for (int ni = 0; ni < 2; ni++) {
        int oc = wave_oc + ni * 16 + lane16;
        float* dst;
        float bias;
        if (oc < 18) { dst = cls_s + (size_t)oc * NPIX; bias = cb[oc]; }
        else if (oc < 54) { dst = bbox_p + (size_t)(oc - 18) * NPIX; bias = bb[oc - 18]; }
        else continue;
#pragma unroll
        for (int mi = 0; mi < 4; mi++) {
            int pxb = px0 + wave_px + mi * 16 + quad * 4;
            if (pxb < NPIX) {
                float4 v = make_float4(acc[mi][ni][0] + bias, acc[mi][ni][1] + bias,
                                       acc[mi][ni][2] + bias, acc[mi][ni][3] + bias);
                *(float4*)(dst + pxb) = v;
            }
        }
    }
}

// ---------------- losses helper ----------------
__device__ __forceinline__ void block_atomic_acc(float v, float* dst) {
    for (int o = 32; o > 0; o >>= 1) v += __shfl_down(v, o);
    if ((threadIdx.x & 63) == 0) atomicAdd(dst, v);
}

// ---------------- decode (+ fused byte-3 hist + fused rpn CE/bbox losses) ----------------
__global__ __launch_bounds__(256) void decode_kernel(
    const float* __restrict__ cls_s, const float* __restrict__ bbox_p,
    const float* __restrict__ anchors,
    const int* __restrict__ rpn_labels,
    const float* __restrict__ rpn_bt, const float* __restrict__ rpn_biw,
    const float* __restrict__ rpn_bow,
    unsigned int* __restrict__ keys, float* __restrict__ boxes,
    unsigned int* __restrict__ ghist, float* __restrict__ accum) {
    __shared__ unsigned int lh[256];
    int t = threadIdx.x;
    lh[t] = 0u;
    __syncthreads();
    int i = blockIdx.x * 256 + t;
    float ce = 0.f, cnt = 0.f, bbl = 0.f;
    if (i < NANCH) {
        int pix = i / AA;
        int a = i - pix * AA;
        float s0 = cls_s[(size_t)a * NPIX + pix];
        float s1 = cls_s[(size_t)(AA + a) * NPIX + pix];
        float d = s1 - s0;
        unsigned int u = __float_as_uint(d);
        unsigned int key = (u & 0x80000000u) ? ~u : (u | 0x80000000u);
        keys[i] = key;
        atomicAdd(&lh[key >> 24], 1u);

        // fused RPN cross-entropy (labels are a-major: a*NPIX + pix)
        int lab = rpn_labels[(size_t)a * NPIX + pix];
        if (lab != -1) {
            float m = fmaxf(s0, s1);
            ce = m + logf(expf(s0 - m) + expf(s1 - m)) - (lab ? s1 : s0);
            cnt = 1.f;
        }

        float dx = bbox_p[(size_t)(4 * a + 0) * NPIX + pix];
        float dy = bbox_p[(size_t)(4 * a + 1) * NPIX + pix];
        float dw = bbox_p[(size_t)(4 * a + 2) * NPIX + pix];
        float dh = bbox_p[(size_t)(4 * a + 3) * NPIX + pix];

        // fused RPN smooth-L1 (HWC layout: e = pix*36 + 4a + j), sigma = 3
        {
            int e = pix * 36 + 4 * a;
            float4 tg = *(const float4*)(rpn_bt + e);
            float4 iw = *(const float4*)(rpn_biw + e);
            float4 ow = *(const float4*)(rpn_bow + e);
            float pr[4] = {dx, dy, dw, dh};
            float tgt[4] = {tg.x, tg.y, tg.z, tg.w};
            float biw[4] = {iw.x, iw.y, iw.z, iw.w};
            float bow[4] = {ow.x, ow.y, ow.z, ow.w};
#pragma unroll
            for (int j = 0; j < 4; j++) {
                float dd = biw[j] * (pr[j] - tgt[j]);
                float ad = fabsf(dd);
                float l = (ad < (1.f / 9.f)) ? dd * dd * 4.5f : ad - (1.f / 18.f);
                bbl += bow[j] * l;
            }
        }

        float ax1 = anchors[(size_t)i * 4 + 0];
        float ay1 = anchors[(size_t)i * 4 + 1];
        float ax2 = anchors[(size_t)i * 4 + 2];
        float ay2 = anchors[(size_t)i * 4 + 3];
        float aw = ax2 - ax1 + 1.f;
        float ah = ay2 - ay1 + 1.f;
        float acx = ax1 + 0.5f * aw;
        float acy = ay1 + 0.5f * ah;
        float pcx = dx * aw + acx;
        float pcy = dy * ah + acy;
        float pw = __expf(dw) * aw;
        float ph = __expf(dh) * ah;
        const float XMAX = 16.f * WW - 1.f;
        const float YMAX = 16.f * HH - 1.f;
        boxes[(size_t)i * 4 + 0] = fminf(fmaxf(pcx - 0.5f * pw, 0.f), XMAX);
        boxes[(size_t)i * 4 + 1] = fminf(fmaxf(pcy - 0.5f * ph, 0.f), YMAX);
        boxes[(size_t)i * 4 + 2] = fminf(fmaxf(pcx + 0.5f * pw, 0.f), XMAX);
        boxes[(size_t)i * 4 + 3] = fminf(fmaxf(pcy + 0.5f * ph, 0.f), YMAX);
    }
    __syncthreads();
    block_atomic_acc(ce, &accum[0]);
    block_atomic_acc(cnt, &accum[1]);
    block_atomic_acc(bbl, &accum[2]);
    if (lh[t]) atomicAdd(&ghist[t], lh[t]);
}

// ---------------- exact top-k (byte-3 histogram precomputed by decode) ----------------
__global__ __launch_bounds__(1024) void topk_kernel(const unsigned int* __restrict__ keys,
                                                    const unsigned int* __restrict__ ghist,
                                                    int* __restrict__ top_idx) {
    const int N = NANCH, K = TOPN;
    __shared__ unsigned int s_prefix;
    __shared__ int s_k;
    __shared__ unsigned int hist[256];
    __shared__ int s_ngt, s_neq;
    __shared__ unsigned long long s_sel[512];
    __shared__ int s_eq[1024];
    int tid = threadIdx.x;
    if (tid == 0) { s_prefix = 0u; s_k = K; }
    __syncthreads();

    for (int d = 3; d >= 0; --d) {
        if (tid < 256) hist[tid] = (d == 3) ? ghist[tid] : 0u;
        __syncthreads();
        unsigned int pfx = s_prefix;
        int shift = d * 8;
        if (d < 3) {
            unsigned int maskHigh = ~((1u << ((d + 1) * 8)) - 1u);
            for (int i = tid; i < N; i += 1024) {
                unsigned int k = keys[i];
                if ((k & maskHigh) == (pfx & maskHigh))
                    atomicAdd(&hist[(k >> shift) & 255u], 1u);
            }
        }
        __syncthreads();
        if (tid == 0) {
            int kk = s_k;
            int cum = 0;
            unsigned int sel = 0;
            for (int v = 255; v >= 0; v--) {
                int hcnt = (int)hist[v];
                if (cum + hcnt >= kk) { sel = (unsigned int)v; s_k = kk - cum; break; }
                cum += hcnt;
            }
            s_prefix = pfx | (sel << shift);
        }
        __syncthreads();
    }
    unsigned int T = s_prefix;
    int krem = s_k;
    if (tid == 0) { s_ngt = 0; s_neq = 0; }
    __syncthreads();
    for (int i = tid; i < N; i += 1024) {
        unsigned int k = keys[i];
        if (k > T) {
            int p = atomicAdd(&s_ngt, 1);
            if (p < 512)
                s_sel[p] = ((unsigned long long)k << 32) | (unsigned int)(~(unsigned int)i);
        } else if (k == T) {
            int p = atomicAdd(&s_neq, 1);
            if (p < 1024) s_eq[p] = i;
        }
    }
    __syncthreads();
    int ngt = min(s_ngt, 512);
    int neq = min(s_neq, 1024);
    for (int e = tid; e < neq; e += 1024) {
        int idx = s_eq[e];
        int rank = 0;
        for (int j = 0; j < neq; j++)
            if (s_eq[j] < idx) rank++;
        if (rank < krem && ngt + rank < 512)
            s_sel[ngt + rank] = ((unsigned long long)T << 32) | (unsigned int)(~(unsigned int)idx);
    }
    __syncthreads();
    for (int p = K + tid; p < 512; p += 1024) s_sel[p] = 0ULL;
    __syncthreads();
    for (unsigned int k2 = 2; k2 <= 512; k2 <<= 1) {
        for (unsigned int j = k2 >> 1; j > 0; j >>= 1) {
            if (tid < 512) {
                int i = tid;
                int ixj = i ^ (int)j;
                if (ixj > i) {
                    unsigned long long a = s_sel[i], cc = s_sel[ixj];
                    bool up = ((i & k2) == 0);
                    if (up ? (a > cc) : (a < cc)) { s_sel[i] = cc; s_sel[ixj] = a; }
                }
            }
            __syncthreads();
        }
    }
    if (tid < K)
        top_idx[tid] = (int)(~(unsigned int)(s_sel[511 - tid] & 0xFFFFFFFFull));
}

// ---------------- roi align from Fpix -> pooled (n,q,c) bf16 ----------------
__global__ __launch_bounds__(256) void roialign_kernel(
    const unsigned short* __restrict__ Fpix, const float* __restrict__ boxes,
    const int* __restrict__ top_idx, unsigned short* __restrict__ pooled) {
    int n = blockIdx.x;
    int q = blockIdx.y;
    int ph = q / 7, pw = q - ph * 7;
    int bi = top_idx[n];
    float x1 = boxes[(size_t)bi * 4 + 0] * (1.f / 16.f);
    float y1 = boxes[(size_t)bi * 4 + 1] * (1.f / 16.f);
    float x2 = boxes[(size_t)bi * 4 + 2] * (1.f / 16.f);
    float y2 = boxes[(size_t)bi * 4 + 3] * (1.f / 16.f);
    float gx = (pw + 0.5f) / 7.f;
    float gy = (ph + 0.5f) / 7.f;
    float xs = fminf(fmaxf(x1 + (x2 - x1) * gx, 0.f), (float)(WW - 1));
    float ys = fminf(fmaxf(y1 + (y2 - y1) * gy, 0.f), (float)(HH - 1));
    float x0f = floorf(xs), y0f = floorf(ys);
    int x0 = (int)x0f, y0 = (int)y0f;
    int x1i = min(x0 + 1, WW - 1);
    int y1i = min(y0 + 1, HH - 1);
    float wx = xs - x0f, wy = ys - y0f;
    float w00 = (1.f - wy) * (1.f - wx), w01 = (1.f - wy) * wx;
    float w10 = wy * (1.f - wx), w11 = wy * wx;
    const unsigned short* r00 = Fpix + (size_t)((y0 + 1) * PW + x0 + 1) * 1024;
    const unsigned short* r01 = Fpix + (size_t)((y0 + 1) * PW + x1i + 1) * 1024;
    const unsigned short* r10 = Fpix + (size_t)((y1i + 1) * PW + x0 + 1) * 1024;
    const unsigned short* r11 = Fpix + (size_t)((y1i + 1) * PW + x1i + 1) * 1024;
    unsigned short* dst = pooled + (size_t)n * KFC + (size_t)q * CIN;
    int c = threadIdx.x * 4;
    ushort4 a = *(const ushort4*)(r00 + c);
    ushort4 b = *(const ushort4*)(r01 + c);
    ushort4 cc = *(const ushort4*)(r10 + c);
    ushort4 d = *(const ushort4*)(r11 + c);
    ushort4 o;
    o.x = f2bf(w00 * bf2f(a.x) + w01 * bf2f(b.x) + w10 * bf2f(cc.x) + w11 * bf2f(d.x));
    o.y = f2bf(w00 * bf2f(a.y) + w01 * bf2f(b.y) + w10 * bf2f(cc.y) + w11 * bf2f(d.y));
    o.z = f2bf(w00 * bf2f(a.z) + w01 * bf2f(b.z) + w10 * bf2f(cc.z) + w11 * bf2f(d.z));
    o.w = f2bf(w00 * bf2f(a.w) + w01 * bf2f(b.w) + w10 * bf2f(cc.w) + w11 * bf2f(d.w));
    *(ushort4*)(dst + c) = o;
}

// ---------------- FC GEMM via MFMA: fc7p[kz] = pooled @ fc_w (kz k-slice) ----------
// grid 512 = 16 kz x 32 j-tiles -> 2 blocks/CU (TLP hides 2-phase barrier stalls).
// kz&7 == XCD -> pooled k-slices stay L2-local. Plain stores to per-kz slab.
__global__ __launch_bounds__(256) void fc_mfma_kernel(
    const unsigned short* __restrict__ pooled, const float* __restrict__ fc_w,
    float* __restrict__ fc7p) {
    __shared__ __align__(16) unsigned short As[320 * 42];
    __shared__ __align__(16) unsigned short Ws[64 * 42];
    const int tid = threadIdx.x;
    const int b = blockIdx.x;
    const int kz = b & (NKZ - 1);
    const int j0 = (b >> 4) * 64;
    const int lane = tid & 63, wv = tid >> 6;
    const int lane16 = lane & 15, quad = lane >> 4;
    const int m0 = wv * 80;
    const int kbase = kz * (KFC / NKZ);   // 3136
    const int g = tid >> 4;               // W staging: krow pair 2g, 2g+1
    const int col4 = (tid & 15) * 4;
    const int NIT = (KFC / NKZ) / 32;     // 98

    f32x4 acc[5][4];
#pragma unroll
    for (int mi = 0; mi < 5; mi++)
#pragma unroll
        for (int ni = 0; ni < 4; ni++) acc[mi][ni] = (f32x4){0.f, 0.f, 0.f, 0.f};

    short8 rA[5];
    float4 rW0[2], rW1[2];

#define LOAD_A(cIdx)                                                              \
    {                                                                             \
        int k0_ = kbase + (cIdx) * 32;                                            \
        _Pragma("unroll")                                                         \
        for (int i = 0; i < 5; i++) {                                             \
            int lid = tid + 256 * i;                                              \
            int row = lid >> 2, seg = lid & 3;                                    \
            rA[i] = (row < TOPN)                                                  \
                  ? *(const short8*)(pooled + (size_t)row * KFC + k0_ + seg * 8)  \
                  : (short8){0, 0, 0, 0, 0, 0, 0, 0};                             \
        }                                                                         \
    }
#define LOAD_W(cIdx, dst)                                                         \
    {                                                                             \
        int k0_ = kbase + (cIdx) * 32;                                            \
        int q_ = k0_ >> 10, c0_ = k0_ & 1023;                                     \
        _Pragma("unroll")                                                         \
        for (int u = 0; u < 2; u++)                                               \
            dst[u] = *(const float4*)(fc_w +                                      \
                ((size_t)(c0_ + 2 * g + u) * 49 + q_) * FCDIM + j0 + col4);       \
    }

    LOAD_A(0);
    LOAD_W(0, rW0);
    LOAD_W(1, rW1);

    for (int c = 0; c < NIT; ++c) {
        __syncthreads();
#pragma unroll
        for (int i = 0; i < 5; i++) {
            int lid = tid + 256 * i;
            int row = lid >> 2, seg = lid & 3;
            *(short8*)&As[row * 42 + seg * 8] = rA[i];
        }
        {
            float* p0 = (float*)&rW0[0];
            float* p1 = (float*)&rW0[1];
#pragma unroll
            for (int v = 0; v < 4; v++)
                *(unsigned int*)&Ws[(col4 + v) * 42 + 2 * g] = cvt_pk_bf16(p0[v], p1[v]);
        }
        if (c + 1 < NIT) LOAD_A(c + 1);
        rW0[0] = rW1[0]; rW0[1] = rW1[1];
        if (c + 2 < NIT) LOAD_W(c + 2, rW1);
        __syncthreads();
        short8 af[5], bfr[4];
#pragma unroll
        for (int mi = 0; mi < 5; mi++)
            af[mi] = *(const short8*)&As[(m0 + mi * 16 + lane16) * 42 + quad * 8];
#pragma unroll
        for (int ni = 0; ni < 4; ni++)
            bfr[ni] = *(const short8*)&Ws[(ni * 16 + lane16) * 42 + quad * 8];
#pragma unroll
        for (int mi = 0; mi < 5; mi++)
#pragma unroll
            for (int ni = 0; ni < 4; ni++)
                acc[mi][ni] = __builtin_amdgcn_mfma_f32_16x16x32_bf16(af[mi], bfr[ni],
                                                                     acc[mi][ni], 0, 0, 0);
    }
#undef LOAD_A
#undef LOAD_W
    float* dst = fc7p + (size_t)kz * (TOPN * FCDIM);
#pragma unroll
    for (int mi = 0; mi < 5; mi++) {
#pragma unroll
        for (int r = 0; r < 4; r++) {
            int m = m0 + mi * 16 + quad * 4 + r;
            if (m < TOPN) {
#pragma unroll
                for (int ni = 0; ni < 4; ni++)
                    dst[(size_t)m * FCDIM + j0 + ni * 16 + lane16] = acc[mi][ni][r];
            }
        }
    }
}

// ---------------- fc7 = sum of NKZ kz slabs + bias + relu ----------------
__global__ void bias_relu_kernel(const float* __restrict__ fc7p,
                                 const float* __restrict__ fc_b,
                                 float* __restrict__ fc7) {
    int i = blockIdx.x * 256 + threadIdx.x;
    if (i < TOPN * FCDIM) {
        float s = 0.f;
#pragma unroll
        for (int z = 0; z < NKZ; z++) s += fc7p[(size_t)z * (TOPN * FCDIM) + i];
        fc7[i] = fmaxf(s + fc_b[i & (FCDIM - 1)], 0.f);
    }
}

// ---------------- head GEMMs ----------------
__global__ __launch_bounds__(128) void head_gemm_kernel(
    const float* __restrict__ fc7,
    const float* __restrict__ cw, const float* __restrict__ cb,
    const float* __restrict__ bw, const float* __restrict__ bb,
    float* __restrict__ cls_score, float* __restrict__ bbox_pred) {
    int n = blockIdx.x;
    __shared__ float row[FCDIM];
    for (int k = threadIdx.x; k < FCDIM; k += 128) row[k] = fc7[(size_t)n * FCDIM + k];
    __syncthreads();
    int t = threadIdx.x;
    if (t < 21) {
        float acc = 0.f;
        for (int k = 0; k < FCDIM; k += 4) {
#pragma unroll
            for (int u = 0; u < 4; u++) acc += row[k + u] * cw[(size_t)(k + u) * 21 + t];
        }
        cls_score[n * 21 + t] = acc + cb[t];
    } else if (t < 105) {
        int oc = t - 21;
        float acc = 0.f;
        for (int k = 0; k < FCDIM; k += 4) {
#pragma unroll
            for (int u = 0; u < 4; u++) acc += row[k + u] * bw[(size_t)(k + u) * 84 + oc];
        }
        bbox_pred[n * 84 + oc] = acc + bb[oc];
    }
}

// ---------------- tail losses: roi CE (blocks 0-1) + roi bbox (blocks 2-100) ---------
__global__ void loss_tail_kernel(const float* __restrict__ cls_score,
                                 const int* __restrict__ labels,
                                 const float* __restrict__ bbox_pred,
                                 const float* __restrict__ tgt,
                                 const float* __restrict__ biw,
                                 const float* __restrict__ bow,
                                 float* __restrict__ acc) {
    int b = blockIdx.x;
    if (b < 2) {
        int n = b * 256 + threadIdx.x;
        float ce = 0.f;
        if (n < TOPN) {
            const float* lg = cls_score + n * 21;
            float m = lg[0];
            for (int j = 1; j < 21; j++) m = fmaxf(m, lg[j]);
            float s = 0.f;
            for (int j = 0; j < 21; j++) s += expf(lg[j] - m);
            ce = m + logf(s) - lg[labels[n]];
        }
        block_atomic_acc(ce, &acc[3]);
    } else {
        int e = (b - 2) * 256 + threadIdx.x;
        float contrib = 0.f;
        if (e < TOPN * 84) {
            float d = biw[e] * (bbox_pred[e] - tgt[e]);
            float ad = fabsf(d);
            float l = (ad < 1.f) ? 0.5f * d * d : ad - 0.5f;
            contrib = bow[e] * l;
        }
        block_atomic_acc(contrib, &acc[4]);
    }
}

__global__ void finalize_kernel(const float* __restrict__ acc, float* __restrict__ out) {
    out[0] = acc[0] / fmaxf(acc[1], 1.f) + acc[2]
           + acc[3] * (1.f / TOPN) + acc[4] * (1.f / TOPN);
}

// ---------------- launch ----------------
extern "C" void kernel_launch(void* const* d_in, const int* in_sizes, int n_in,
                              void* d_out, int out_size, void* d_ws, size_t ws_size,
                              hipStream_t stream) {
    const float* net_conv   = (const float*)d_in[0];
    const float* rpn_w      = (const float*)d_in[1];
    const float* rpn_b      = (const float*)d_in[2];
    const float* rpn_cls_w  = (const float*)d_in[3];
    const float* rpn_cls_b  = (const float*)d_in[4];
    const float* rpn_bbox_w = (const float*)d_in[5];
    const float* rpn_bbox_b = (const float*)d_in[6];
    const float* fc_w       = (const float*)d_in[7];
    const float* fc_b       = (const float*)d_in[8];
    const float* cls_w      = (const float*)d_in[9];
    const float* cls_b      = (const float*)d_in[10];
    const float* bbox_w     = (const float*)d_in[11];
    const float* bbox_b     = (const float*)d_in[12];
    const float* anchors    = (const float*)d_in[13];
    const float* rpn_bt     = (const float*)d_in[14];
    const float* rpn_biw    = (const float*)d_in[15];
    const float* rpn_bow    = (const float*)d_in[16];
    const float* roi_bt     = (const float*)d_in[17];
    const float* roi_biw    = (const float*)d_in[18];
    const float* roi_bow    = (const float*)d_in[19];
    const int* rpn_labels   = (const int*)d_in[20];
    const int* roi_labels   = (const int*)d_in[21];

    char* base = (char*)d_ws;
    unsigned short* Fpix = (unsigned short*)base;
    const size_t FPIX_BYTES = (size_t)FPIX_ROWS * 1024 * 2;  // 20,463,616
    unsigned short* Wb = (unsigned short*)(base + FPIX_BYTES);
    unsigned short* rpn = (unsigned short*)(base + 29900800);  // [9120][512] bf16
    unsigned short* pooled = (unsigned short*)(base + FPIX_BYTES);
    size_t off = 50569216;
    float* cls_s = (float*)(base + off);      off += 656640;
    float* bbox_p = (float*)(base + off);     off += 1313280;
    unsigned int* keys = (unsigned int*)(base + off); off += 328448;
    float* boxes = (float*)(base + off);      off += 1313280;
    int* top_idx = (int*)(base + off);        off += 1280;
    float* cls_score = (float*)(base + off);  off += 25600;
    float* bbox_pred = (float*)(base + off);  off += 100864;
    float* fc7 = (float*)(base + off);        off += 2457600;
    float* accum = (float*)(base + off);      off += 256;
    unsigned int* hist = (unsigned int*)(base + off); off += 1024;
    float* fc7p = (float*)(base + off);       off += (size_t)NKZ * TOPN * FCDIM * 4;
    float* out = (float*)d_out;

    zero4_kernel<<<(int)((FPIX_BYTES / 16 + 255) / 256), 256, 0, stream>>>((float4*)Fpix,
                                                                           (int)(FPIX_BYTES / 16));
    fpix_fill_kernel<<<dim3(143, 16), 256, 0, stream>>>(net_conv, Fpix);
    wb_fill_kernel<<<2048, 256, 0, stream>>>(rpn_w, Wb);
    zero_kernel<<<2, 256, 0, stream>>>(accum, 64 + 256);   // accum + hist

    conv_mfma_kernel<<<1280, 256, 0, stream>>>(Fpix, Wb, rpn_b, rpn);
    heads_mfma_kernel<<<72, 256, 0, stream>>>(rpn, rpn_cls_w, rpn_cls_b,
                                              rpn_bbox_w, rpn_bbox_b, cls_s, bbox_p);
    decode_kernel<<<(NANCH + 255) / 256, 256, 0, stream>>>(cls_s, bbox_p, anchors,
                                                           rpn_labels, rpn_bt, rpn_biw,
                                                           rpn_bow, keys, boxes, hist, accum);
    topk_kernel<<<1, 1024, 0, stream>>>(keys, hist, top_idx);
    roialign_kernel<<<dim3(300, 49), 256, 0, stream>>>(Fpix, boxes, top_idx, pooled);
    fc_mfma_kernel<<<512, 256, 0, stream>>>(pooled, fc_w, fc7p);
    bias_relu_kernel<<<(TOPN * FCDIM + 255) / 256, 256, 0, stream>>>(fc7p, fc_b, fc7);
    head_gemm_kernel<<<300, 128, 0, stream>>>(fc7, cls_w, cls_b, bbox_w, bbox_b,
                                              cls_score, bbox_pred);
    loss_tail_kernel<<<101, 256, 0, stream>>>(cls_score, roi_labels, bbox_pred, roi_bt,
                                              roi_biw, roi_bow, accum);
    finalize_kernel<<<1, 1, 0, stream>>>(accum, out);
}